// Round 6
// baseline (1083.209 us; speedup 1.0000x reference)
//
#include <hip/hip_runtime.h>
#include <cstdint>
#include <cstddef>

typedef float f32x4 __attribute__((ext_vector_type(4)));
typedef short s16x8 __attribute__((ext_vector_type(8)));
typedef unsigned short u16;

static __device__ __forceinline__ u16 f2bf(float f) {
    uint32_t x = __float_as_uint(f);
    x += 0x7fffu + ((x >> 16) & 1u);   // round-to-nearest-even to bf16
    return (u16)(x >> 16);
}
static __device__ __forceinline__ float bf2f(u16 h) {
    return __uint_as_float(((uint32_t)h) << 16);
}

// Raw barrier with ONLY an LDS drain (no vmcnt) — prefetch loads / hseq
// stores stay in flight across the per-step barrier.
static __device__ __forceinline__ void bar_lds() {
    asm volatile("s_waitcnt lgkmcnt(0)" ::: "memory");
    __builtin_amdgcn_s_barrier();
    asm volatile("" ::: "memory");
}

// ---------------- zero the pipeline flags (every launch; replay-safe) ------
__global__ void k_zero(int* __restrict__ p, int n) {
    int i = blockIdx.x * 256 + threadIdx.x;
    if (i < n) p[i] = 0;
}

// ---------------- split fp32 -> bf16 hi/lo ----------------
__global__ void k_split(const float* __restrict__ src, u16* __restrict__ hi,
                        u16* __restrict__ lo, int n) {
    int i = blockIdx.x * 256 + threadIdx.x;
    if (i < n) {
        float f = src[i];
        u16 h = f2bf(f);
        hi[i] = h;
        lo[i] = f2bf(f - bf2f(h));
    }
}

// ---------------- split-bf16 GEMM (layer-0 input projection) ----------------
__global__ __launch_bounds__(256, 2)
void k_gemm(const float* __restrict__ A, const u16* __restrict__ Wh,
            const u16* __restrict__ Wl, const float* __restrict__ bias,
            float* __restrict__ C, int K) {
    __shared__ __align__(16) u16 sm[32768];   // 64 KB

    const int tid  = threadIdx.x;
    const int lane = tid & 63;
    const int wave = tid >> 6;
    const int wm = wave >> 1, wn = wave & 1;

    int g = blockIdx.x;                 // 0..767
    int xcd = g & 7, ix = g >> 3;       // 96 per xcd
    int q3 = ix / 3;
    int mb = xcd + 8 * q3;              // 0..255
    int nb = ix - 3 * q3;               // 0..2
    const long m0 = (long)mb * 128;
    const int  n0 = nb * 128;

    f32x4 acc[4][4];
    const f32x4 vzero = {0.f, 0.f, 0.f, 0.f};
#pragma unroll
    for (int i = 0; i < 4; ++i)
#pragma unroll
        for (int j = 0; j < 4; ++j) acc[i][j] = vzero;

    const int ar = tid >> 1;
    const int ac = (tid & 1) * 16;
    const float* aptr = A + (m0 + ar) * (long)K + ac;
    const int br = tid >> 2;
    const int bc = (tid & 3) * 8;
    const u16* bhp = Wh + (long)(n0 + br) * K + bc;
    const u16* blp = Wl + (long)(n0 + br) * K + bc;

    const int ksteps = K >> 5;
    f32x4 a0, a1, a2, a3;

    {
        a0 = *(const f32x4*)(aptr + 0);
        a1 = *(const f32x4*)(aptr + 4);
        a2 = *(const f32x4*)(aptr + 8);
        a3 = *(const f32x4*)(aptr + 12);
#pragma unroll
        for (int c = 0; c < 2; ++c) {
            const u16* sh = bhp + (long)(c * 64) * K;
            const u16* sl = blp + (long)(c * 64) * K;
            u16* dh = &sm[8192  + c * 2048 + wave * 512];
            u16* dl = &sm[12288 + c * 2048 + wave * 512];
            __builtin_amdgcn_global_load_lds((const __attribute__((address_space(1))) void*)sh,
                                             (__attribute__((address_space(3))) void*)dh, 16, 0, 0);
            __builtin_amdgcn_global_load_lds((const __attribute__((address_space(1))) void*)sl,
                                             (__attribute__((address_space(3))) void*)dl, 16, 0, 0);
        }
        float fr[16] = {a0.x,a0.y,a0.z,a0.w, a1.x,a1.y,a1.z,a1.w,
                        a2.x,a2.y,a2.z,a2.w, a3.x,a3.y,a3.z,a3.w};
        s16x8 h0, h1, l0, l1;
#pragma unroll
        for (int i = 0; i < 8; ++i) {
            u16 hh = f2bf(fr[i]);     h0[i] = (short)hh; l0[i] = (short)f2bf(fr[i] - bf2f(hh));
            u16 hh2 = f2bf(fr[8+i]);  h1[i] = (short)hh2; l1[i] = (short)f2bf(fr[8+i] - bf2f(hh2));
        }
        u16* dh = &sm[ar * 32 + ac];
        u16* dl = &sm[4096 + ar * 32 + ac];
        *(s16x8*)dh = h0; *(s16x8*)(dh + 8) = h1;
        *(s16x8*)dl = l0; *(s16x8*)(dl + 8) = l1;
    }
    __syncthreads();

    for (int ks = 0; ks < ksteps; ++ks) {
        const int cur = ks & 1, nxt = cur ^ 1;
        const bool more = (ks + 1 < ksteps);
        if (more) {
            const int k0 = (ks + 1) << 5;
            a0 = *(const f32x4*)(aptr + k0 + 0);
            a1 = *(const f32x4*)(aptr + k0 + 4);
            a2 = *(const f32x4*)(aptr + k0 + 8);
            a3 = *(const f32x4*)(aptr + k0 + 12);
#pragma unroll
            for (int c = 0; c < 2; ++c) {
                const u16* sh = bhp + (long)(c * 64) * K + k0;
                const u16* sl = blp + (long)(c * 64) * K + k0;
                u16* dh = &sm[nxt * 16384 + 8192  + c * 2048 + wave * 512];
                u16* dl = &sm[nxt * 16384 + 12288 + c * 2048 + wave * 512];
                __builtin_amdgcn_global_load_lds((const __attribute__((address_space(1))) void*)sh,
                                                 (__attribute__((address_space(3))) void*)dh, 16, 0, 0);
                __builtin_amdgcn_global_load_lds((const __attribute__((address_space(1))) void*)sl,
                                                 (__attribute__((address_space(3))) void*)dl, 16, 0, 0);
            }
        }
        {
            const u16* base = &sm[cur * 16384];
            const int koff = (lane >> 4) * 8;
            const int rsel = lane & 15;
            s16x8 ah[4], al[4];
#pragma unroll
            for (int f = 0; f < 4; ++f) {
                int row = wm * 64 + f * 16 + rsel;
                ah[f] = *(const s16x8*)&base[row * 32 + koff];
                al[f] = *(const s16x8*)&base[4096 + row * 32 + koff];
            }
#pragma unroll
            for (int j = 0; j < 4; ++j) {
                int row = wn * 64 + j * 16 + rsel;
                s16x8 bh = *(const s16x8*)&base[8192  + row * 32 + koff];
                s16x8 bl = *(const s16x8*)&base[12288 + row * 32 + koff];
#pragma unroll
                for (int f = 0; f < 4; ++f) {
                    acc[f][j] = __builtin_amdgcn_mfma_f32_16x16x32_bf16(ah[f], bh, acc[f][j], 0, 0, 0);
                    acc[f][j] = __builtin_amdgcn_mfma_f32_16x16x32_bf16(ah[f], bl, acc[f][j], 0, 0, 0);
                    acc[f][j] = __builtin_amdgcn_mfma_f32_16x16x32_bf16(al[f], bh, acc[f][j], 0, 0, 0);
                }
            }
        }
        if (more) {
            float fr[16] = {a0.x,a0.y,a0.z,a0.w, a1.x,a1.y,a1.z,a1.w,
                            a2.x,a2.y,a2.z,a2.w, a3.x,a3.y,a3.z,a3.w};
            s16x8 h0, h1, l0, l1;
#pragma unroll
            for (int i = 0; i < 8; ++i) {
                u16 hh = f2bf(fr[i]);     h0[i] = (short)hh; l0[i] = (short)f2bf(fr[i] - bf2f(hh));
                u16 hh2 = f2bf(fr[8+i]);  h1[i] = (short)hh2; l1[i] = (short)f2bf(fr[8+i] - bf2f(hh2));
            }
            u16* dh = &sm[nxt * 16384 + ar * 32 + ac];
            u16* dl = &sm[nxt * 16384 + 4096 + ar * 32 + ac];
            *(s16x8*)dh = h0; *(s16x8*)(dh + 8) = h1;
            *(s16x8*)dl = l0; *(s16x8*)(dl + 8) = l1;
        }
        __syncthreads();
    }

    const int r0 = (lane >> 4) << 2;
    const int cn = lane & 15;
#pragma unroll
    for (int f = 0; f < 4; ++f) {
        const long mrow = m0 + wm * 64 + f * 16 + r0;
#pragma unroll
        for (int j = 0; j < 4; ++j) {
            const int n = n0 + wn * 64 + j * 16 + cn;
            const float bv = bias[n];
            float* o = C + mrow * 384 + n;
#pragma unroll
            for (int jj = 0; jj < 4; ++jj) o[(long)jj * 384] = acc[f][j][jj] + bv;
        }
    }
}

// =================== fused pipeline kernel ===================
// grid = 256 blocks x 512 threads, 1 block/CU (LDS-forced).
//   blocks 0..3   : L0 recurrence, 16 batches each (MFMA-batched)
//   blocks 4..7   : L1 recurrence, 16 batches each + MLP head
//   blocks 8..255 : GEMM workers (248): xg1 = h1 @ w_ih1^T + b_ih1
//
// MFMA recurrence: per step, H[16,128] @ whh^T[384,128] via split-bf16
// 16x16x32 MFMA. Wave w owns gate cols [16w,16w+16) of r,z,n (N-tiles
// w, w+8, w+16) -> its C frags ARE its h-slice: no reduce phase.
// h shared via fragment-major LDS [hcol>>3][bat][8] (conflict-free b128
// reads), double-buffered -> ONE barrier per step. C-init = prefetched
// xg_t (+b_hh); accn seeded with b_hh_n only (n = tanh(xn + r*(h.w+b))).

struct SmemRecur {
    u16 frag[2][2][2048];    // [buf][hi/lo][(hcol>>3)*128 + bat*8 + (hcol&7)]
    float h2buf[16][128];    // head staging (L1, after loop)
};
struct SmemGemm  { u16 ah[2048]; u16 al[2048]; };
union Smem {
    SmemRecur r;
    SmemGemm  g;
    char force_one_block_per_cu[98304];   // 96KB: strictly 1 block/CU
};

// prefetch xg(t) into registers (12 scalar loads); L1 waits chunk counter
#define PF(R_, Z_, N_, T_) do {                                               \
    const int _pt = (T_);                                                     \
    if (_pt < 512) {                                                          \
        if (!isL0 && (_pt & 15) == 0) {                                       \
            if (lane == 0) {                                                  \
                while (atomicAdd(&waitcnt[g * 32 + (_pt >> 4)], 0) < 16)      \
                    __builtin_amdgcn_s_sleep(8);                              \
            }                                                                 \
            __threadfence();                                                  \
        }                                                                     \
        const size_t _o = (size_t)_pt * 384;                                  \
        R_[0] = bp0[_o]; Z_[0] = bp0[_o + 128]; N_[0] = bp0[_o + 256];        \
        R_[1] = bp1[_o]; Z_[1] = bp1[_o + 128]; N_[1] = bp1[_o + 256];        \
        R_[2] = bp2[_o]; Z_[2] = bp2[_o + 128]; N_[2] = bp2[_o + 256];        \
        R_[3] = bp3[_o]; Z_[3] = bp3[_o + 128]; N_[3] = bp3[_o + 256];        \
    } } while (0)

#define RSTEP(T_, R_, Z_, N_) do {                                            \
    const int _t = (T_);                                                      \
    f32x4 accr = {R_[0] + bhr, R_[1] + bhr, R_[2] + bhr, R_[3] + bhr};        \
    f32x4 accz = {Z_[0] + bhz, Z_[1] + bhz, Z_[2] + bhz, Z_[3] + bhz};        \
    f32x4 accn = {bhn, bhn, bhn, bhn};                                        \
    const float _xn0 = N_[0], _xn1 = N_[1], _xn2 = N_[2], _xn3 = N_[3];       \
    {                                                                         \
        const u16* _hb = &sm.frag[p][0][0];                                   \
        const u16* _lb = &sm.frag[p][1][0];                                   \
        _Pragma("unroll")                                                     \
        for (int kk = 0; kk < 4; ++kk) {                                      \
            const int _fo = (kk * 4 + qk) * 128 + col * 8;                    \
            s16x8 _ah = *(const s16x8*)&_hb[_fo];                             \
            s16x8 _al = *(const s16x8*)&_lb[_fo];                             \
            accr = __builtin_amdgcn_mfma_f32_16x16x32_bf16(_ah, wbh[0][kk], accr, 0, 0, 0); \
            accz = __builtin_amdgcn_mfma_f32_16x16x32_bf16(_ah, wbh[1][kk], accz, 0, 0, 0); \
            accn = __builtin_amdgcn_mfma_f32_16x16x32_bf16(_ah, wbh[2][kk], accn, 0, 0, 0); \
            accr = __builtin_amdgcn_mfma_f32_16x16x32_bf16(_ah, wbl[0][kk], accr, 0, 0, 0); \
            accz = __builtin_amdgcn_mfma_f32_16x16x32_bf16(_ah, wbl[1][kk], accz, 0, 0, 0); \
            accn = __builtin_amdgcn_mfma_f32_16x16x32_bf16(_ah, wbl[2][kk], accn, 0, 0, 0); \
            accr = __builtin_amdgcn_mfma_f32_16x16x32_bf16(_al, wbh[0][kk], accr, 0, 0, 0); \
            accz = __builtin_amdgcn_mfma_f32_16x16x32_bf16(_al, wbh[1][kk], accz, 0, 0, 0); \
            accn = __builtin_amdgcn_mfma_f32_16x16x32_bf16(_al, wbh[2][kk], accn, 0, 0, 0); \
        }                                                                     \
    }                                                                         \
    {                                                                         \
        u16* _wh = &sm.frag[p ^ 1][0][0];                                     \
        u16* _wl = &sm.frag[p ^ 1][1][0];                                     \
        const float _xna[4] = {_xn0, _xn1, _xn2, _xn3};                       \
        _Pragma("unroll")                                                     \
        for (int j = 0; j < 4; ++j) {                                         \
            const float _r = 1.f / (1.f + __expf(-accr[j]));                  \
            const float _z = 1.f / (1.f + __expf(-accz[j]));                  \
            float _a = _xna[j] + _r * accn[j];                                \
            _a = fminf(fmaxf(_a, -15.f), 15.f);                               \
            const float _e = __expf(2.f * _a);                                \
            const float _n = (_e - 1.f) / (_e + 1.f);                         \
            const float _h = (1.f - _z) * _n + _z * hold[j];                  \
            hold[j] = _h;                                                     \
            const u16 _hh = f2bf(_h);                                         \
            _wh[fa + j * 8] = _hh;                                            \
            _wl[fa + j * 8] = f2bf(_h - bf2f(_hh));                           \
            if (isL0) hseq[hb0 + (size_t)j * 65536 + (size_t)_t * 128] = _h;  \
        }                                                                     \
    }                                                                         \
    PF(R_, Z_, N_, _t + 2);                                                   \
    const bool _pub = isL0 && ((_t & 15) == 15) && (_t < 511);                \
    if (_pub) asm volatile("s_waitcnt vmcnt(12)" ::: "memory");               \
    bar_lds();                                                                \
    if (_pub && tid == 0) {                                                   \
        __threadfence();                                                      \
        atomicExch(&setflag[g * 32 + (_t >> 4)], 1);                          \
    }                                                                         \
    p ^= 1;                                                                   \
} while (0)

__device__ __forceinline__ void recur_role(
    bool isL0, int g, const float* __restrict__ xg,
    const float* __restrict__ whh, const float* __restrict__ bhh,
    float* __restrict__ hseq, int* __restrict__ setflag, int* __restrict__ waitcnt,
    const float* __restrict__ wfc1, const float* __restrict__ bfc1,
    const float* __restrict__ wfc2, const float* __restrict__ bfc2,
    float* __restrict__ out, SmemRecur& sm)
{
    const int tid = threadIdx.x, lane = tid & 63, w = tid >> 6;   // 8 waves
    const int col = lane & 15;   // gate-col offset (B-row) / batch (A-row) on reads
    const int qk  = lane >> 4;   // k-chunk (frags) / batch-group (C rows)
    const int gr  = 16 * w + col;   // this lane's gate row & h-column

    // persistent w_hh B-frags: [gate r/z/n][kstep] hi/lo  (96 VGPR)
    s16x8 wbh[3][4], wbl[3][4];
#pragma unroll
    for (int gs = 0; gs < 3; ++gs)
#pragma unroll
        for (int kk = 0; kk < 4; ++kk) {
            const float* p = whh + (size_t)(gs * 128 + gr) * 128 + kk * 32 + qk * 8;
            f32x4 v0 = *(const f32x4*)p, v1 = *(const f32x4*)(p + 4);
            float fv[8] = {v0[0], v0[1], v0[2], v0[3], v1[0], v1[1], v1[2], v1[3]};
            s16x8 hh, ll;
#pragma unroll
            for (int i = 0; i < 8; ++i) {
                u16 h = f2bf(fv[i]); hh[i] = (short)h; ll[i] = (short)f2bf(fv[i] - bf2f(h));
            }
            wbh[gs][kk] = hh; wbl[gs][kk] = ll;
        }
    const float bhr = bhh[gr], bhz = bhh[128 + gr], bhn = bhh[256 + gr];
    f32x4 hold = {0.f, 0.f, 0.f, 0.f};

    const size_t bstr = (size_t)512 * 384;
    const float* bp0 = xg + (size_t)(16 * g + qk * 4 + 0) * bstr + gr;
    const float* bp1 = xg + (size_t)(16 * g + qk * 4 + 1) * bstr + gr;
    const float* bp2 = xg + (size_t)(16 * g + qk * 4 + 2) * bstr + gr;
    const float* bp3 = xg + (size_t)(16 * g + qk * 4 + 3) * bstr + gr;
    const size_t hb0 = ((size_t)(16 * g) + qk * 4) * 65536 + gr;   // hseq base
    const int fa = ((gr >> 3) * 128) + (qk * 32) + (gr & 7);       // frag write base

    // zero h-frag buffer 0 (h(-1) = 0)
    {
        uint32_t* z32 = (uint32_t*)&sm.frag[0][0][0];
#pragma unroll
        for (int i = 0; i < 4; ++i) z32[tid + 512 * i] = 0;
    }
    f32x4 rA, zA, nA, rB, zB, nB;
    PF(rA, zA, nA, 0);   // L1: waits chunk 0
    PF(rB, zB, nB, 1);
    __syncthreads();

    int p = 0;
    for (int i = 0; i < 256; ++i) {
        RSTEP(2 * i,     rA, zA, nA);
        RSTEP(2 * i + 1, rB, zB, nB);
    }

    if (isL0) {   // final chunk publish
        asm volatile("s_waitcnt vmcnt(0)" ::: "memory");
        __syncthreads();
        if (tid == 0) { __threadfence(); atomicExch(&setflag[g * 32 + 31], 1); }
    }

    if (!isL0) {   // fused MLP head for this block's 16 batches
#pragma unroll
        for (int j = 0; j < 4; ++j) sm.h2buf[qk * 4 + j][gr] = hold[j];
        __syncthreads();
        const int hb_ = tid >> 5, l_ = tid & 31;
        const float* hv = sm.h2buf[hb_];
        const float* w0 = wfc1 + l_ * 128;
        const float* w1 = wfc1 + (l_ + 32) * 128;
        float d0 = bfc1[l_], d1 = bfc1[l_ + 32];
#pragma unroll 4
        for (int c2 = 0; c2 < 128; ++c2) {
            d0 = fmaf(hv[c2], w0[c2], d0);
            d1 = fmaf(hv[c2], w1[c2], d1);
        }
        float pv = fmaxf(d0, 0.f) * wfc2[l_] + fmaxf(d1, 0.f) * wfc2[l_ + 32];
#pragma unroll
        for (int off = 16; off > 0; off >>= 1) pv += __shfl_down(pv, off, 32);
        if (l_ == 0) out[16 * g + hb_] = pv + bfc2[0];
    }
}

__device__ __forceinline__ void worker_role(
    int wk, const float* __restrict__ h1, float* __restrict__ xg,
    const float* __restrict__ wih1, const float* __restrict__ bih1,
    int* __restrict__ h1flag, int* __restrict__ xgcnt, SmemGemm& sm)
{
    const int tid = threadIdx.x, lane = tid & 63, w = tid >> 6;   // 8 waves
    const int rsel = lane & 15, koff = (lane >> 4) * 8;

    // persistent W_ih1 fragments: wave w owns n-frags {3w, 3w+1, 3w+2}
    s16x8 bh[3][4], bl[3][4];
    float bias[3];
#pragma unroll
    for (int nfi = 0; nfi < 3; ++nfi) {
        const int n = (3 * w + nfi) * 16 + rsel;
        bias[nfi] = bih1[n];
#pragma unroll
        for (int ks = 0; ks < 4; ++ks) {
            const float* p = wih1 + n * 128 + ks * 32 + koff;
            f32x4 v0 = *(const f32x4*)p, v1 = *(const f32x4*)(p + 4);
            float fv[8] = {v0[0], v0[1], v0[2], v0[3], v1[0], v1[1], v1[2], v1[3]};
            s16x8 hh, ll;
#pragma unroll
            for (int i = 0; i < 8; ++i) {
                u16 h = f2bf(fv[i]); hh[i] = (short)h; ll[i] = (short)f2bf(fv[i] - bf2f(h));
            }
            bh[nfi][ks] = hh; bl[nfi][ks] = ll;
        }
    }

    for (int j = wk; j < 2048; j += 248) {
        const int c = j >> 6, b = j & 63;     // chunk 0..31, batch 0..63
        if (tid == 0) {
            while (atomicAdd(&h1flag[(b >> 4) * 32 + c], 0) == 0)
                __builtin_amdgcn_s_sleep(8);
            __threadfence();
        }
        __syncthreads();
        // stage A = h1 rows (b, 16c..16c+15): fp32 -> split bf16 hi/lo in LDS
        if (tid < 256) {
            const int r = tid >> 4, c0 = (tid & 15) * 8;
            const float* p = h1 + ((size_t)(b * 512 + c * 16 + r)) * 128 + c0;
            f32x4 v0 = *(const f32x4*)p, v1 = *(const f32x4*)(p + 4);
            float fv[8] = {v0[0], v0[1], v0[2], v0[3], v1[0], v1[1], v1[2], v1[3]};
            s16x8 hh, ll;
#pragma unroll
            for (int i = 0; i < 8; ++i) {
                u16 h = f2bf(fv[i]); hh[i] = (short)h; ll[i] = (short)f2bf(fv[i] - bf2f(h));
            }
            const int sc = c0 ^ ((r & 7) << 3);   // XOR-swizzle (T2)
            *(s16x8*)&sm.ah[r * 128 + sc] = hh;
            *(s16x8*)&sm.al[r * 128 + sc] = ll;
        }
        __syncthreads();

        f32x4 acc[3];
        const f32x4 vz = {0.f, 0.f, 0.f, 0.f};
        acc[0] = vz; acc[1] = vz; acc[2] = vz;
#pragma unroll
        for (int ks = 0; ks < 4; ++ks) {
            const int si = rsel * 128 + ((ks * 32 + koff) ^ ((rsel & 7) << 3));
            s16x8 a_h = *(const s16x8*)&sm.ah[si];
            s16x8 a_l = *(const s16x8*)&sm.al[si];
#pragma unroll
            for (int nfi = 0; nfi < 3; ++nfi) {
                acc[nfi] = __builtin_amdgcn_mfma_f32_16x16x32_bf16(a_h, bh[nfi][ks], acc[nfi], 0, 0, 0);
                acc[nfi] = __builtin_amdgcn_mfma_f32_16x16x32_bf16(a_h, bl[nfi][ks], acc[nfi], 0, 0, 0);
                acc[nfi] = __builtin_amdgcn_mfma_f32_16x16x32_bf16(a_l, bh[nfi][ks], acc[nfi], 0, 0, 0);
            }
        }
        // epilogue: xg1 rows overwrite consumed xg0 rows (safe: flag order)
#pragma unroll
        for (int nfi = 0; nfi < 3; ++nfi) {
            const int n = (3 * w + nfi) * 16 + rsel;
#pragma unroll
            for (int jj = 0; jj < 4; ++jj) {
                const int m = (lane >> 4) * 4 + jj;
                xg[((size_t)(b * 512 + c * 16 + m)) * 384 + n] = acc[nfi][jj] + bias[nfi];
            }
        }
        __syncthreads();   // drains stores (vmcnt0) + LDS reuse safety
        if (tid == 0) {
            __threadfence();
            atomicAdd(&xgcnt[(b >> 4) * 32 + c], 1);
        }
    }
}

__global__ __launch_bounds__(512, 1)
void k_fused(float* __restrict__ xg, float* __restrict__ h1,
             const float* __restrict__ whh0, const float* __restrict__ bhh0,
             const float* __restrict__ wih1, const float* __restrict__ bih1,
             const float* __restrict__ whh1, const float* __restrict__ bhh1,
             const float* __restrict__ wfc1, const float* __restrict__ bfc1,
             const float* __restrict__ wfc2, const float* __restrict__ bfc2,
             float* __restrict__ out, int* __restrict__ h1flag, int* __restrict__ xgcnt)
{
    __shared__ __align__(16) Smem sm;
    const int bid = blockIdx.x;
    if (bid < 4) {
        recur_role(true, bid, xg, whh0, bhh0, h1, h1flag, nullptr,
                   nullptr, nullptr, nullptr, nullptr, nullptr, sm.r);
    } else if (bid < 8) {
        recur_role(false, bid - 4, xg, whh1, bhh1, nullptr, nullptr, xgcnt,
                   wfc1, bfc1, wfc2, bfc2, out, sm.r);
    } else {
        worker_role(bid - 8, h1, xg, wih1, bih1, h1flag, xgcnt, sm.g);
    }
}

extern "C" void kernel_launch(void* const* d_in, const int* in_sizes, int n_in,
                              void* d_out, int out_size, void* d_ws, size_t ws_size,
                              hipStream_t stream) {
    const float* x     = (const float*)d_in[0];
    const float* w_ih0 = (const float*)d_in[1];
    const float* w_hh0 = (const float*)d_in[2];
    const float* b_ih0 = (const float*)d_in[3];
    const float* b_hh0 = (const float*)d_in[4];
    const float* w_ih1 = (const float*)d_in[5];
    const float* w_hh1 = (const float*)d_in[6];
    const float* b_ih1 = (const float*)d_in[7];
    const float* b_hh1 = (const float*)d_in[8];
    const float* w_fc1 = (const float*)d_in[9];
    const float* b_fc1 = (const float*)d_in[10];
    const float* w_fc2 = (const float*)d_in[11];
    const float* b_fc2 = (const float*)d_in[12];
    float* out = (float*)d_out;
    (void)in_sizes; (void)n_in; (void)out_size; (void)ws_size;

    char* ws = (char*)d_ws;
    float* xg     = (float*)(ws + 0);          // 32768*384*4 (xg0, then xg1 in place)
    float* h1     = (float*)(ws + 50331648);   // 32768*128*4
    u16*   w0h    = (u16*)(ws + 67108864);     // 786432*2
    u16*   w0l    = (u16*)(ws + 68681728);     // 786432*2
    int*   h1flag = (int*)(ws + 70254592);     // 128 ints (4 L0 blocks x 32 chunks)
    int*   xgcnt  = h1flag + 128;              // 128 ints (counters, target 16)

    k_zero<<<1, 256, 0, stream>>>(h1flag, 256);
    k_split<<<3072, 256, 0, stream>>>(w_ih0, w0h, w0l, 384 * 2048);
    k_gemm<<<768, 256, 0, stream>>>(x, w0h, w0l, b_ih0, xg, 2048);
    k_fused<<<256, 512, 0, stream>>>(xg, h1, w_hh0, b_hh0, w_ih1, b_ih1,
                                     w_hh1, b_hh1, w_fc1, b_fc1, w_fc2, b_fc2,
                                     out, h1flag, xgcnt);
}

// Round 7
// 1055.218 us; speedup vs baseline: 1.0265x; 1.0265x over previous
//
#include <hip/hip_runtime.h>
#include <cstdint>
#include <cstddef>

typedef float f32x4 __attribute__((ext_vector_type(4)));
typedef float f32x2 __attribute__((ext_vector_type(2)));
typedef short s16x8 __attribute__((ext_vector_type(8)));
typedef unsigned short u16;

static __device__ __forceinline__ u16 f2bf(float f) {
    uint32_t x = __float_as_uint(f);
    x += 0x7fffu + ((x >> 16) & 1u);   // round-to-nearest-even to bf16
    return (u16)(x >> 16);
}
static __device__ __forceinline__ float bf2f(u16 h) {
    return __uint_as_float(((uint32_t)h) << 16);
}
static __device__ __forceinline__ void split8(const float* fv, s16x8& hh, s16x8& ll) {
#pragma unroll
    for (int i = 0; i < 8; ++i) {
        u16 h = f2bf(fv[i]); hh[i] = (short)h; ll[i] = (short)f2bf(fv[i] - bf2f(h));
    }
}

// Raw barrier with ONLY an LDS drain (no vmcnt) — prefetch loads / hseq
// stores stay in flight across the per-step barriers.
static __device__ __forceinline__ void bar_lds() {
    asm volatile("s_waitcnt lgkmcnt(0)" ::: "memory");
    __builtin_amdgcn_s_barrier();
    asm volatile("" ::: "memory");
}

#define GLDS(SRC, DST) __builtin_amdgcn_global_load_lds( \
    (const __attribute__((address_space(1))) void*)(SRC), \
    (__attribute__((address_space(3))) void*)(DST), 16, 0, 0)

// ---------------- zero the pipeline flags (every launch; replay-safe) ------
__global__ void k_zero(int* __restrict__ p, int n) {
    int i = blockIdx.x * 256 + threadIdx.x;
    if (i < n) p[i] = 0;
}

// ---------------- split fp32 -> bf16 hi/lo ----------------
__global__ void k_split(const float* __restrict__ src, u16* __restrict__ hi,
                        u16* __restrict__ lo, int n) {
    int i = blockIdx.x * 256 + threadIdx.x;
    if (i < n) {
        float f = src[i];
        u16 h = f2bf(f);
        hi[i] = h;
        lo[i] = f2bf(f - bf2f(h));
    }
}

// =================== fused pipeline kernel ===================
// grid = 256 blocks x 512 threads, 1 block/CU (LDS-forced).
//   blocks   0..63 : L0 recurrence (1 batch each), gated on gemmcnt[tc]
//   blocks  64..127: 1 early G0 tile, then L1 recurrence + MLP head
//   blocks 128..255: workers: 5-6 G0 tiles (tc-major priority) with xg1
//                    drains between tiles and at ksteps 16/32/48, then
//                    blocking xg1 finish.
// G0 task (768 total): (tc 0..31, bg 0..7, nb 0..2): xg0 tile of
// 128 rows (8 batches x 16 t) x 128 cols, K=2048, split-bf16 MFMA.

struct SmemRecur { float hsh[128]; float hp[8][384]; };
struct SmemG0    { u16 buf[2][4][4096]; };   // [buf][Ah,Al,Bh,Bl][128*32] 64KB
struct SmemX     { u16 ah[2048]; u16 al[2048]; int decision; };
struct SmemWorker { SmemG0 g0; SmemX x; };
union Smem {
    SmemRecur r;
    SmemWorker w;
    char force_one_block_per_cu[98304];   // 96KB: strictly 1 block/CU
};

// ---- xg1 task: xg1 chunk (b, c) = h1[b, 16c..16c+16) @ W_ih1^T + b_ih1 ----
__device__ void do_xg1_task(int j, int* __restrict__ xgflag,
        const float* __restrict__ h1, float* __restrict__ xg,
        const u16* __restrict__ w1h, const u16* __restrict__ w1l,
        const float* __restrict__ bih1, SmemX& smx)
{
    const int c = j >> 6, b = j & 63;
    const int tid = threadIdx.x, lane = tid & 63, wv = tid >> 6;
    const int rsel = lane & 15, koff = (lane >> 4) * 8;

    if (tid < 256) {   // stage h1 rows -> split bf16 hi/lo in LDS
        const int r = tid >> 4, c0 = (tid & 15) * 8;
        const float* p = h1 + ((size_t)(b * 512 + c * 16 + r)) * 128 + c0;
        f32x4 v0 = *(const f32x4*)p, v1 = *(const f32x4*)(p + 4);
        float fv[8] = {v0[0],v0[1],v0[2],v0[3], v1[0],v1[1],v1[2],v1[3]};
        s16x8 hh, ll; split8(fv, hh, ll);
        const int sc = c0 ^ ((r & 7) << 3);   // XOR-swizzle (T2)
        *(s16x8*)&smx.ah[r * 128 + sc] = hh;
        *(s16x8*)&smx.al[r * 128 + sc] = ll;
    }
    __syncthreads();

    f32x4 acc[3];
    const f32x4 vz = {0.f, 0.f, 0.f, 0.f};
    acc[0] = vz; acc[1] = vz; acc[2] = vz;
#pragma unroll
    for (int ks = 0; ks < 4; ++ks) {
        const int si = rsel * 128 + ((ks * 32 + koff) ^ ((rsel & 7) << 3));
        s16x8 a_h = *(const s16x8*)&smx.ah[si];
        s16x8 a_l = *(const s16x8*)&smx.al[si];
#pragma unroll
        for (int nf = 0; nf < 3; ++nf) {
            const int n = (3 * wv + nf) * 16 + rsel;
            s16x8 bh = *(const s16x8*)&w1h[(size_t)n * 128 + ks * 32 + koff];
            s16x8 bl = *(const s16x8*)&w1l[(size_t)n * 128 + ks * 32 + koff];
            acc[nf] = __builtin_amdgcn_mfma_f32_16x16x32_bf16(a_h, bh, acc[nf], 0, 0, 0);
            acc[nf] = __builtin_amdgcn_mfma_f32_16x16x32_bf16(a_h, bl, acc[nf], 0, 0, 0);
            acc[nf] = __builtin_amdgcn_mfma_f32_16x16x32_bf16(a_l, bh, acc[nf], 0, 0, 0);
        }
    }
#pragma unroll
    for (int nf = 0; nf < 3; ++nf) {
        const int n = (3 * wv + nf) * 16 + rsel;
        const float bv = bih1[n];
#pragma unroll
        for (int jj = 0; jj < 4; ++jj) {
            const int m = (lane >> 4) * 4 + jj;
            xg[((size_t)(b * 512 + c * 16 + m)) * 384 + n] = acc[nf][jj] + bv;
        }
    }
    __syncthreads();   // drains stores (vmcnt0)
    if (tid == 0) { __threadfence(); atomicExch(&xgflag[b * 32 + c], 1); }
}

// non-blocking drain of ready xg1 tasks (up to cap)
__device__ int drain_ready(int nextq, int cap, int* __restrict__ h1flag,
        int* __restrict__ xgflag, const float* __restrict__ h1,
        float* __restrict__ xg, const u16* __restrict__ w1h,
        const u16* __restrict__ w1l, const float* __restrict__ bih1, SmemX& smx)
{
    const int tid = threadIdx.x;
    for (int it = 0; it < cap && nextq < 2048; ++it) {
        if (tid == 0) {
            const int c = nextq >> 6, b = nextq & 63;
            int v = atomicAdd(&h1flag[b * 32 + c], 0);
            if (v) __threadfence();
            smx.decision = v;
        }
        __syncthreads();
        const int go = smx.decision;
        __syncthreads();
        if (!go) break;
        do_xg1_task(nextq, xgflag, h1, xg, w1h, w1l, bih1, smx);
        nextq += 128;
    }
    return nextq;
}

// ---- one G0 tile: xg0 for task T = tc*24 + bg*3 + nb ----
__device__ __attribute__((noinline)) void g0_tile(int T,
        const float* __restrict__ x, const u16* __restrict__ w0h,
        const u16* __restrict__ w0l, const float* __restrict__ bih0,
        float* __restrict__ xg, int* __restrict__ gemmcnt, SmemG0& g,
        int* nextq_io, int* h1flag, int* xgflag, const float* h1,
        const u16* w1h, const u16* w1l, const float* bih1, SmemX* smx)
{
    const int tc = T / 24, rem = T - tc * 24;
    const int bg = rem / 3, nb = rem - bg * 3;
    const int tid = threadIdx.x, lane = tid & 63, wv = tid >> 6;
    const int wm = wv >> 2, wn = wv & 3;          // 2 x 4 wave grid
    const int rsel = lane & 15, koff = (lane >> 4) * 8;

    const int ar = tid >> 2, ak = (tid & 3) * 8;
    const float* aptr = x + ((size_t)(bg * 8 + (ar >> 4)) * 512 + tc * 16 + (ar & 15)) * 2048 + ak;
    const u16* bhp = w0h + (size_t)(nb * 128 + (tid >> 2)) * 2048 + ak;
    const u16* blp = w0l + (size_t)(nb * 128 + (tid >> 2)) * 2048 + ak;

    f32x4 acc[4][2];
    const f32x4 vz = {0.f, 0.f, 0.f, 0.f};
#pragma unroll
    for (int f = 0; f < 4; ++f) { acc[f][0] = vz; acc[f][1] = vz; }

    {   // prologue: stage ks=0 into buf 0
        GLDS(bhp, &g.buf[0][2][0] + tid * 8);
        GLDS(blp, &g.buf[0][3][0] + tid * 8);
        f32x4 a0 = *(const f32x4*)aptr, a1 = *(const f32x4*)(aptr + 4);
        float fv[8] = {a0[0],a0[1],a0[2],a0[3], a1[0],a1[1],a1[2],a1[3]};
        s16x8 hh, ll; split8(fv, hh, ll);
        *(s16x8*)&g.buf[0][0][ar * 32 + ak] = hh;
        *(s16x8*)&g.buf[0][1][ar * 32 + ak] = ll;
    }
    __syncthreads();

    for (int ks = 0; ks < 64; ++ks) {
        const int cur = ks & 1, nxt = cur ^ 1;
        const bool more = ks < 63;
        f32x4 a0, a1;
        if (more) {
            const int k0 = (ks + 1) * 32;
            GLDS(bhp + k0, &g.buf[nxt][2][0] + tid * 8);
            GLDS(blp + k0, &g.buf[nxt][3][0] + tid * 8);
            a0 = *(const f32x4*)(aptr + k0);
            a1 = *(const f32x4*)(aptr + k0 + 4);
        }
        {
            const u16* base = &g.buf[cur][0][0];
            s16x8 ah[4], al[4], bh2[2], bl2[2];
#pragma unroll
            for (int f = 0; f < 4; ++f) {
                const int row = wm * 64 + f * 16 + rsel;
                ah[f] = *(const s16x8*)&base[row * 32 + koff];
                al[f] = *(const s16x8*)&base[4096 + row * 32 + koff];
            }
#pragma unroll
            for (int j = 0; j < 2; ++j) {
                const int row = wn * 32 + j * 16 + rsel;
                bh2[j] = *(const s16x8*)&base[8192  + row * 32 + koff];
                bl2[j] = *(const s16x8*)&base[12288 + row * 32 + koff];
            }
#pragma unroll
            for (int j = 0; j < 2; ++j)
#pragma unroll
                for (int f = 0; f < 4; ++f) {
                    acc[f][j] = __builtin_amdgcn_mfma_f32_16x16x32_bf16(ah[f], bh2[j], acc[f][j], 0, 0, 0);
                    acc[f][j] = __builtin_amdgcn_mfma_f32_16x16x32_bf16(ah[f], bl2[j], acc[f][j], 0, 0, 0);
                    acc[f][j] = __builtin_amdgcn_mfma_f32_16x16x32_bf16(al[f], bh2[j], acc[f][j], 0, 0, 0);
                }
        }
        if (more) {
            float fv[8] = {a0[0],a0[1],a0[2],a0[3], a1[0],a1[1],a1[2],a1[3]};
            s16x8 hh, ll; split8(fv, hh, ll);
            *(s16x8*)&g.buf[nxt][0][ar * 32 + ak] = hh;
            *(s16x8*)&g.buf[nxt][1][ar * 32 + ak] = ll;
        }
        __syncthreads();
        // mid-tile xg1 drains keep L1's lag bounded (~1/4 tile)
        if (smx != nullptr && (ks == 16 || ks == 32 || ks == 48)) {
            *nextq_io = drain_ready(*nextq_io, 2, h1flag, xgflag, h1, xg,
                                    w1h, w1l, bih1, *smx);
        }
    }

#pragma unroll
    for (int f = 0; f < 4; ++f)
#pragma unroll
        for (int j = 0; j < 2; ++j) {
            const int n = nb * 128 + wn * 32 + j * 16 + rsel;
            const float bv = bih0[n];
#pragma unroll
            for (int jj = 0; jj < 4; ++jj) {
                const int m = wm * 64 + f * 16 + (lane >> 4) * 4 + jj;
                const size_t row = (size_t)(bg * 8 + (m >> 4)) * 512 + tc * 16 + (m & 15);
                xg[row * 384 + n] = acc[f][j][jj] + bv;
            }
        }
    __syncthreads();   // drains stores (vmcnt0)
    if (tid == 0) { __threadfence(); atomicAdd(&gemmcnt[tc], 1); }
}

// ---- recurrence (r5 structure, + gemmcnt gate for L0) ----

#define R_ISSUE(BUF, G) do {                                                  \
    const int _G = (G);                                                       \
    if (_G < 128 && tid < 128) {                                              \
        if ((_G & 3) == 0) {                                                  \
            if (isL0) {                                                       \
                if ((tid & 63) == 0) {                                        \
                    while (atomicAdd(&gemmcnt[_G >> 2], 0) < 24)              \
                        __builtin_amdgcn_s_sleep(64);                         \
                }                                                             \
                __threadfence();                                              \
            } else {                                                          \
                if ((tid & 63) == 0) {                                        \
                    while (atomicAdd(&waitflag[b * 32 + (_G >> 2)], 0) == 0)  \
                        __builtin_amdgcn_s_sleep(8);                          \
                }                                                             \
                __threadfence();                                              \
            }                                                                 \
        }                                                                     \
        const float* _p = xgb + (size_t)(4 * _G) * 384 + tid;                 \
        BUF[0] = _p[0];    BUF[1] = _p[128];   BUF[2]  = _p[256];             \
        BUF[3] = _p[384];  BUF[4] = _p[512];   BUF[5]  = _p[640];             \
        BUF[6] = _p[768];  BUF[7] = _p[896];   BUF[8]  = _p[1024];            \
        BUF[9] = _p[1152]; BUF[10] = _p[1280]; BUF[11] = _p[1408];            \
    } } while (0)

#define R_STEP(T, BUF, J) do {                                                \
    const int _t = (T);                                                       \
    f32x4 _h0 = *(const f32x4*)(sm.hsh + 16 * w + 0);                         \
    f32x4 _h1 = *(const f32x4*)(sm.hsh + 16 * w + 4);                         \
    f32x4 _h2 = *(const f32x4*)(sm.hsh + 16 * w + 8);                         \
    f32x4 _h3 = *(const f32x4*)(sm.hsh + 16 * w + 12);                        \
    float _ha[16];                                                            \
    _ha[0]=_h0[0];  _ha[1]=_h0[1];  _ha[2]=_h0[2];  _ha[3]=_h0[3];            \
    _ha[4]=_h1[0];  _ha[5]=_h1[1];  _ha[6]=_h1[2];  _ha[7]=_h1[3];            \
    _ha[8]=_h2[0];  _ha[9]=_h2[1];  _ha[10]=_h2[2]; _ha[11]=_h2[3];           \
    _ha[12]=_h3[0]; _ha[13]=_h3[1]; _ha[14]=_h3[2]; _ha[15]=_h3[3];           \
    float _s0=0.f,_s1=0.f,_s2=0.f,_s3=0.f,_s4=0.f,_s5=0.f;                    \
    _Pragma("unroll")                                                         \
    for (int _i = 0; _i < 16; ++_i) {                                         \
        const float _hv = _ha[_i];                                            \
        _s0 = fmaf(_hv, wr[0][_i], _s0); _s1 = fmaf(_hv, wr[1][_i], _s1);     \
        _s2 = fmaf(_hv, wr[2][_i], _s2); _s3 = fmaf(_hv, wr[3][_i], _s3);     \
        _s4 = fmaf(_hv, wr[4][_i], _s4); _s5 = fmaf(_hv, wr[5][_i], _s5);     \
    }                                                                         \
    *(f32x2*)&sm.hp[w][g6 + 0] = (f32x2){_s0, _s1};                           \
    *(f32x2*)&sm.hp[w][g6 + 2] = (f32x2){_s2, _s3};                           \
    *(f32x2*)&sm.hp[w][g6 + 4] = (f32x2){_s4, _s5};                           \
    const bool _pub = isL0 && _t > 0 && (_t & 15) == 0;                       \
    if (_pub && tid < 128) asm volatile("s_waitcnt vmcnt(12)" ::: "memory");  \
    bar_lds();                                                                \
    if (_pub && tid == 0) {                                                   \
        __threadfence();                                                      \
        atomicExch(&setflag[b * 32 + ((_t >> 4) - 1)], 1);                    \
    }                                                                         \
    if (tid < 128) {                                                          \
        const int _c = tid;                                                   \
        float _hr = bhr, _hz = bhz, _hn = bhn;                                \
        _Pragma("unroll")                                                     \
        for (int _q = 0; _q < 8; ++_q) {                                      \
            _hr += sm.hp[_q][_c];                                             \
            _hz += sm.hp[_q][128 + _c];                                       \
            _hn += sm.hp[_q][256 + _c];                                       \
        }                                                                     \
        const float _xr = BUF[(J) * 3 + 0];                                   \
        const float _xz = BUF[(J) * 3 + 1];                                   \
        const float _xn = BUF[(J) * 3 + 2];                                   \
        const float _r = 1.f / (1.f + __expf(-(_xr + _hr)));                  \
        const float _z = 1.f / (1.f + __expf(-(_xz + _hz)));                  \
        float _a = _xn + _r * _hn;                                            \
        _a = fminf(fmaxf(_a, -15.f), 15.f);                                   \
        const float _e = __expf(2.f * _a);                                    \
        const float _n = (_e - 1.f) / (_e + 1.f);                             \
        hreg = (1.f - _z) * _n + _z * hreg;                                   \
        sm.hsh[_c] = hreg;                                                    \
        if (isL0) hseq[((size_t)(b * 512 + _t)) * 128 + _c] = hreg;           \
    }                                                                         \
    bar_lds();                                                                \
} while (0)

__device__ void recur_role(
    bool isL0, int b, const float* __restrict__ xg,
    const float* __restrict__ whh, const float* __restrict__ bhh,
    float* __restrict__ hseq, int* __restrict__ setflag, int* __restrict__ waitflag,
    int* __restrict__ gemmcnt,
    const float* __restrict__ wfc1, const float* __restrict__ bfc1,
    const float* __restrict__ wfc2, const float* __restrict__ bfc2,
    float* __restrict__ out, SmemRecur& sm)
{
    const int tid  = threadIdx.x;       // 0..511
    const int w    = tid >> 6;          // k-slice 0..7 (wave-uniform)
    const int lane = tid & 63;
    const int g6   = 6 * lane;          // first of this lane's 6 gates
    (void)lane;

    // per-lane weights: wr[j][i] = whh[(g6+j)*128 + 16w + i]
    float wr[6][16];
#pragma unroll
    for (int j = 0; j < 6; ++j) {
        const float* p = whh + (size_t)(g6 + j) * 128 + 16 * w;
#pragma unroll
        for (int i4 = 0; i4 < 4; ++i4) {
            f32x4 v = *(const f32x4*)(p + 4 * i4);
            wr[j][4*i4+0] = v[0]; wr[j][4*i4+1] = v[1];
            wr[j][4*i4+2] = v[2]; wr[j][4*i4+3] = v[3];
        }
    }
    float bhr = 0.f, bhz = 0.f, bhn = 0.f, hreg = 0.f;
    if (tid < 128) {
        bhr = bhh[tid]; bhz = bhh[128 + tid]; bhn = bhh[256 + tid];
        sm.hsh[tid] = 0.f;
    }
    const float* xgb = xg + (size_t)b * 512 * 384;

    float pA[12], pB[12];
    R_ISSUE(pA, 0);
    R_ISSUE(pB, 1);
    __syncthreads();   // hsh init visible

    for (int gp = 0; gp < 64; ++gp) {
        const int t0 = gp * 8;
        R_STEP(t0 + 0, pA, 0); R_STEP(t0 + 1, pA, 1);
        R_STEP(t0 + 2, pA, 2); R_STEP(t0 + 3, pA, 3);
        R_ISSUE(pA, 2 * gp + 2);
        R_STEP(t0 + 4, pB, 0); R_STEP(t0 + 5, pB, 1);
        R_STEP(t0 + 6, pB, 2); R_STEP(t0 + 7, pB, 3);
        R_ISSUE(pB, 2 * gp + 3);
    }

    if (isL0) {   // final chunk publish
        if (tid < 128) asm volatile("s_waitcnt vmcnt(0)" ::: "memory");
        __syncthreads();
        if (tid == 0) { __threadfence(); atomicExch(&setflag[b * 32 + 31], 1); }
    }

    if (!isL0 && tid < 64) {   // fused MLP head
        const float* wv = wfc1 + tid * 128;
        float acc = bfc1[tid];
#pragma unroll 8
        for (int c = 0; c < 128; ++c) acc = fmaf(sm.hsh[c], wv[c], acc);
        float p = fmaxf(acc, 0.f) * wfc2[tid];
#pragma unroll
        for (int off = 32; off > 0; off >>= 1) p += __shfl_down(p, off);
        if (tid == 0) out[b] = p + bfc2[0];
    }
}

__device__ void worker_role(int wk, const float* __restrict__ x,
        const u16* __restrict__ w0h, const u16* __restrict__ w0l,
        const float* __restrict__ bih0, float* __restrict__ xg,
        const float* __restrict__ h1, const u16* __restrict__ w1h,
        const u16* __restrict__ w1l, const float* __restrict__ bih1,
        int* __restrict__ gemmcnt, int* __restrict__ h1flag,
        int* __restrict__ xgflag, SmemWorker& sw)
{
    const int tid = threadIdx.x;
    int nextq = wk;   // xg1 tasks j = wk + 128n, n < 16

#pragma unroll 1
    for (int k = 0; k < 6; ++k) {
        const int T = 64 + wk + 128 * k;   // tc-major priority order
        if (T < 768) {
            g0_tile(T, x, w0h, w0l, bih0, xg, gemmcnt, sw.g0,
                    &nextq, h1flag, xgflag, h1, w1h, w1l, bih1, &sw.x);
            nextq = drain_ready(nextq, 4, h1flag, xgflag, h1, xg,
                                w1h, w1l, bih1, sw.x);
        }
    }
    // blocking finish of remaining xg1 tasks (in order)
    while (nextq < 2048) {
        if (tid == 0) {
            const int c = nextq >> 6, b = nextq & 63;
            while (atomicAdd(&h1flag[b * 32 + c], 0) == 0)
                __builtin_amdgcn_s_sleep(8);
            __threadfence();
        }
        __syncthreads();
        do_xg1_task(nextq, xgflag, h1, xg, w1h, w1l, bih1, sw.x);
        nextq += 128;
    }
}

__global__ __launch_bounds__(512, 2)
void k_fused(const float* __restrict__ x, float* __restrict__ xg,
             float* __restrict__ h1,
             const u16* __restrict__ w0h, const u16* __restrict__ w0l,
             const float* __restrict__ bih0,
             const float* __restrict__ whh0, const float* __restrict__ bhh0,
             const u16* __restrict__ w1h, const u16* __restrict__ w1l,
             const float* __restrict__ bih1,
             const float* __restrict__ whh1, const float* __restrict__ bhh1,
             const float* __restrict__ wfc1, const float* __restrict__ bfc1,
             const float* __restrict__ wfc2, const float* __restrict__ bfc2,
             float* __restrict__ out, int* __restrict__ gemmcnt,
             int* __restrict__ h1flag, int* __restrict__ xgflag)
{
    __shared__ __align__(16) Smem sm;
    const int bid = blockIdx.x;
    if (bid < 64) {
        recur_role(true, bid, xg, whh0, bhh0, h1, h1flag, xgflag, gemmcnt,
                   nullptr, nullptr, nullptr, nullptr, nullptr, sm.r);
    } else if (bid < 128) {
        // one early G0 tile (T = 0..63 covers the most urgent tc slices)
        g0_tile(bid - 64, x, w0h, w0l, bih0, xg, gemmcnt, sm.w.g0,
                nullptr, nullptr, nullptr, nullptr, nullptr, nullptr, nullptr,
                nullptr);
        recur_role(false, bid - 64, xg, whh1, bhh1, nullptr, nullptr, xgflag,
                   gemmcnt, wfc1, bfc1, wfc2, bfc2, out, sm.r);
    } else {
        worker_role(bid - 128, x, w0h, w0l, bih0, xg, h1, w1h, w1l, bih1,
                    gemmcnt, h1flag, xgflag, sm.w);
    }
}

extern "C" void kernel_launch(void* const* d_in, const int* in_sizes, int n_in,
                              void* d_out, int out_size, void* d_ws, size_t ws_size,
                              hipStream_t stream) {
    const float* x     = (const float*)d_in[0];
    const float* w_ih0 = (const float*)d_in[1];
    const float* w_hh0 = (const float*)d_in[2];
    const float* b_ih0 = (const float*)d_in[3];
    const float* b_hh0 = (const float*)d_in[4];
    const float* w_ih1 = (const float*)d_in[5];
    const float* w_hh1 = (const float*)d_in[6];
    const float* b_ih1 = (const float*)d_in[7];
    const float* b_hh1 = (const float*)d_in[8];
    const float* w_fc1 = (const float*)d_in[9];
    const float* b_fc1 = (const float*)d_in[10];
    const float* w_fc2 = (const float*)d_in[11];
    const float* b_fc2 = (const float*)d_in[12];
    float* out = (float*)d_out;
    (void)in_sizes; (void)n_in; (void)out_size; (void)ws_size;

    char* ws = (char*)d_ws;
    float* xg     = (float*)(ws + 0);          // 32768*384*4 (xg0, then xg1 in place)
    float* h1     = (float*)(ws + 50331648);   // 32768*128*4
    u16*   w0h    = (u16*)(ws + 67108864);     // 786432*2
    u16*   w0l    = (u16*)(ws + 68681728);     // 786432*2
    u16*   w1h    = (u16*)(ws + 70254592);     // 49152*2
    u16*   w1l    = (u16*)(ws + 70352896);     // 49152*2
    int*   h1flag = (int*)(ws + 70451200);     // 2048 ints
    int*   xgflag = h1flag + 2048;             // 2048 ints
    int*   gemmcnt = xgflag + 2048;            // 32 ints

    k_zero<<<17, 256, 0, stream>>>(h1flag, 4128);
    k_split<<<3072, 256, 0, stream>>>(w_ih0, w0h, w0l, 384 * 2048);
    k_split<<<192, 256, 0, stream>>>(w_ih1, w1h, w1l, 384 * 128);
    k_fused<<<256, 512, 0, stream>>>(x, xg, h1, w0h, w0l, b_ih0, w_hh0, b_hh0,
                                     w1h, w1l, b_ih1, w_hh1, b_hh1,
                                     w_fc1, b_fc1, w_fc2, b_fc2,
                                     out, gemmcnt, h1flag, xgflag);
}

// Round 9
// 937.041 us; speedup vs baseline: 1.1560x; 1.1261x over previous
//
#include <hip/hip_runtime.h>
#include <cstdint>
#include <cstddef>

typedef float f32x4 __attribute__((ext_vector_type(4)));
typedef short s16x8 __attribute__((ext_vector_type(8)));
typedef unsigned short u16;

static __device__ __forceinline__ u16 f2bf(float f) {
    uint32_t x = __float_as_uint(f);
    x += 0x7fffu + ((x >> 16) & 1u);   // round-to-nearest-even to bf16
    return (u16)(x >> 16);
}
static __device__ __forceinline__ float bf2f(u16 h) {
    return __uint_as_float(((uint32_t)h) << 16);
}

// Raw barrier with ONLY an LDS drain (no vmcnt) — prefetch loads / hseq
// stores stay in flight across the per-step barrier.
static __device__ __forceinline__ void bar_lds() {
    asm volatile("s_waitcnt lgkmcnt(0)" ::: "memory");
    __builtin_amdgcn_s_barrier();
    asm volatile("" ::: "memory");
}

// ---------------- zero the pipeline flags (every launch; replay-safe) ------
__global__ void k_zero(int* __restrict__ p, int n) {
    int i = blockIdx.x * 256 + threadIdx.x;
    if (i < n) p[i] = 0;
}

// ---------------- split fp32 -> bf16 hi/lo ----------------
__global__ void k_split(const float* __restrict__ src, u16* __restrict__ hi,
                        u16* __restrict__ lo, int n) {
    int i = blockIdx.x * 256 + threadIdx.x;
    if (i < n) {
        float f = src[i];
        u16 h = f2bf(f);
        hi[i] = h;
        lo[i] = f2bf(f - bf2f(h));
    }
}

// ---------------- split-bf16 GEMM (layer-0 input projection) ----------------
__global__ __launch_bounds__(256, 2)
void k_gemm(const float* __restrict__ A, const u16* __restrict__ Wh,
            const u16* __restrict__ Wl, const float* __restrict__ bias,
            float* __restrict__ C, int K) {
    __shared__ __align__(16) u16 sm[32768];   // 64 KB

    const int tid  = threadIdx.x;
    const int lane = tid & 63;
    const int wave = tid >> 6;
    const int wm = wave >> 1, wn = wave & 1;

    int g = blockIdx.x;                 // 0..767
    int xcd = g & 7, ix = g >> 3;       // 96 per xcd
    int q3 = ix / 3;
    int mb = xcd + 8 * q3;              // 0..255
    int nb = ix - 3 * q3;               // 0..2
    const long m0 = (long)mb * 128;
    const int  n0 = nb * 128;

    f32x4 acc[4][4];
    const f32x4 vzero = {0.f, 0.f, 0.f, 0.f};
#pragma unroll
    for (int i = 0; i < 4; ++i)
#pragma unroll
        for (int j = 0; j < 4; ++j) acc[i][j] = vzero;

    const int ar = tid >> 1;
    const int ac = (tid & 1) * 16;
    const float* aptr = A + (m0 + ar) * (long)K + ac;
    const int br = tid >> 2;
    const int bc = (tid & 3) * 8;
    const u16* bhp = Wh + (long)(n0 + br) * K + bc;
    const u16* blp = Wl + (long)(n0 + br) * K + bc;

    const int ksteps = K >> 5;
    f32x4 a0, a1, a2, a3;

    {
        a0 = *(const f32x4*)(aptr + 0);
        a1 = *(const f32x4*)(aptr + 4);
        a2 = *(const f32x4*)(aptr + 8);
        a3 = *(const f32x4*)(aptr + 12);
#pragma unroll
        for (int c = 0; c < 2; ++c) {
            const u16* sh = bhp + (long)(c * 64) * K;
            const u16* sl = blp + (long)(c * 64) * K;
            u16* dh = &sm[8192  + c * 2048 + wave * 512];
            u16* dl = &sm[12288 + c * 2048 + wave * 512];
            __builtin_amdgcn_global_load_lds((const __attribute__((address_space(1))) void*)sh,
                                             (__attribute__((address_space(3))) void*)dh, 16, 0, 0);
            __builtin_amdgcn_global_load_lds((const __attribute__((address_space(1))) void*)sl,
                                             (__attribute__((address_space(3))) void*)dl, 16, 0, 0);
        }
        float fr[16] = {a0.x,a0.y,a0.z,a0.w, a1.x,a1.y,a1.z,a1.w,
                        a2.x,a2.y,a2.z,a2.w, a3.x,a3.y,a3.z,a3.w};
        s16x8 h0, h1, l0, l1;
#pragma unroll
        for (int i = 0; i < 8; ++i) {
            u16 hh = f2bf(fr[i]);     h0[i] = (short)hh; l0[i] = (short)f2bf(fr[i] - bf2f(hh));
            u16 hh2 = f2bf(fr[8+i]);  h1[i] = (short)hh2; l1[i] = (short)f2bf(fr[8+i] - bf2f(hh2));
        }
        u16* dh = &sm[ar * 32 + ac];
        u16* dl = &sm[4096 + ar * 32 + ac];
        *(s16x8*)dh = h0; *(s16x8*)(dh + 8) = h1;
        *(s16x8*)dl = l0; *(s16x8*)(dl + 8) = l1;
    }
    __syncthreads();

    for (int ks = 0; ks < ksteps; ++ks) {
        const int cur = ks & 1, nxt = cur ^ 1;
        const bool more = (ks + 1 < ksteps);
        if (more) {
            const int k0 = (ks + 1) << 5;
            a0 = *(const f32x4*)(aptr + k0 + 0);
            a1 = *(const f32x4*)(aptr + k0 + 4);
            a2 = *(const f32x4*)(aptr + k0 + 8);
            a3 = *(const f32x4*)(aptr + k0 + 12);
#pragma unroll
            for (int c = 0; c < 2; ++c) {
                const u16* sh = bhp + (long)(c * 64) * K + k0;
                const u16* sl = blp + (long)(c * 64) * K + k0;
                u16* dh = &sm[nxt * 16384 + 8192  + c * 2048 + wave * 512];
                u16* dl = &sm[nxt * 16384 + 12288 + c * 2048 + wave * 512];
                __builtin_amdgcn_global_load_lds((const __attribute__((address_space(1))) void*)sh,
                                                 (__attribute__((address_space(3))) void*)dh, 16, 0, 0);
                __builtin_amdgcn_global_load_lds((const __attribute__((address_space(1))) void*)sl,
                                                 (__attribute__((address_space(3))) void*)dl, 16, 0, 0);
            }
        }
        {
            const u16* base = &sm[cur * 16384];
            const int koff = (lane >> 4) * 8;
            const int rsel = lane & 15;
            s16x8 ah[4], al[4];
#pragma unroll
            for (int f = 0; f < 4; ++f) {
                int row = wm * 64 + f * 16 + rsel;
                ah[f] = *(const s16x8*)&base[row * 32 + koff];
                al[f] = *(const s16x8*)&base[4096 + row * 32 + koff];
            }
#pragma unroll
            for (int j = 0; j < 4; ++j) {
                int row = wn * 64 + j * 16 + rsel;
                s16x8 bh = *(const s16x8*)&base[8192  + row * 32 + koff];
                s16x8 bl = *(const s16x8*)&base[12288 + row * 32 + koff];
#pragma unroll
                for (int f = 0; f < 4; ++f) {
                    acc[f][j] = __builtin_amdgcn_mfma_f32_16x16x32_bf16(ah[f], bh, acc[f][j], 0, 0, 0);
                    acc[f][j] = __builtin_amdgcn_mfma_f32_16x16x32_bf16(ah[f], bl, acc[f][j], 0, 0, 0);
                    acc[f][j] = __builtin_amdgcn_mfma_f32_16x16x32_bf16(al[f], bh, acc[f][j], 0, 0, 0);
                }
            }
        }
        if (more) {
            float fr[16] = {a0.x,a0.y,a0.z,a0.w, a1.x,a1.y,a1.z,a1.w,
                            a2.x,a2.y,a2.z,a2.w, a3.x,a3.y,a3.z,a3.w};
            s16x8 h0, h1, l0, l1;
#pragma unroll
            for (int i = 0; i < 8; ++i) {
                u16 hh = f2bf(fr[i]);     h0[i] = (short)hh; l0[i] = (short)f2bf(fr[i] - bf2f(hh));
                u16 hh2 = f2bf(fr[8+i]);  h1[i] = (short)hh2; l1[i] = (short)f2bf(fr[8+i] - bf2f(hh2));
            }
            u16* dh = &sm[nxt * 16384 + ar * 32 + ac];
            u16* dl = &sm[nxt * 16384 + 4096 + ar * 32 + ac];
            *(s16x8*)dh = h0; *(s16x8*)(dh + 8) = h1;
            *(s16x8*)dl = l0; *(s16x8*)(dl + 8) = l1;
        }
        __syncthreads();
    }

    const int r0 = (lane >> 4) << 2;
    const int cn = lane & 15;
#pragma unroll
    for (int f = 0; f < 4; ++f) {
        const long mrow = m0 + wm * 64 + f * 16 + r0;
#pragma unroll
        for (int j = 0; j < 4; ++j) {
            const int n = n0 + wn * 64 + j * 16 + cn;
            const float bv = bias[n];
            float* o = C + mrow * 384 + n;
#pragma unroll
            for (int jj = 0; jj < 4; ++jj) o[(long)jj * 384] = acc[f][j][jj] + bv;
        }
    }
}

// =================== fused pipeline kernel ===================
// grid = 256 blocks x 512 threads, 1 block/CU (LDS-forced).
//   blocks   0..63 : L0 recurrence (1 batch), publish h1flag per 16 steps
//   blocks  64..127: L1 recurrence (consume xgflag) + MLP head
//   blocks 128..255: workers: xg1 = h1 @ w_ih1^T + b_ih1 (r5-proven)
//
// Recurrence step (ONE barrier): 4-lane group <-> hidden unit j; lane
// lq owns k-quarter [32lq,32lq+32) and all 3 gates of j (96 FMA).
// Quad butterfly (shfl_xor 1,2) -> all lanes hold hr,hz,hn -> redundant
// activation -> h_j register-local.
// hsh is DOUBLE-BUFFERED (r8 post-mortem): step t reads hsh[t&1], writes
// h(t) to hsh[(t+1)&1] -> no write-after-read race across waves with a
// single barrier. h(511) ends in hsh[0] (512 even).

struct SmemRecur { float hsh[2][128]; };
struct SmemGemm  { u16 ah[2048]; u16 al[2048]; };
union Smem {
    SmemRecur r;
    SmemGemm  g;
    char force_one_block_per_cu[98304];   // 96KB: strictly 1 block/CU
};

#define R_ISSUE(BUF, T_) do {                                                 \
    const int _pt = (T_);                                                     \
    if (_pt < 512) {                                                          \
        if (!isL0 && (_pt & 15) == 0) {                                       \
            if ((tid & 63) == 0) {                                            \
                while (atomicAdd(&waitflag[b * 32 + (_pt >> 4)], 0) == 0)     \
                    __builtin_amdgcn_s_sleep(8);                              \
            }                                                                 \
            __threadfence();                                                  \
        }                                                                     \
        const float* _p = xgb + (size_t)_pt * 384 + j;                        \
        BUF[0] = _p[0]; BUF[1] = _p[128]; BUF[2] = _p[256];                   \
    } } while (0)

// P_: parity of step T_ (compile-time 0/1). Reads hsh[P_], writes hsh[P_^1].
#define R_STEP(T_, BUF, P_) do {                                              \
    const int _t = (T_);                                                      \
    const float* _hb = sm.hsh[P_] + 32 * lq;                                  \
    float _s0 = 0.f, _s1 = 0.f, _s2 = 0.f;                                    \
    _Pragma("unroll")                                                         \
    for (int _i = 0; _i < 8; ++_i) {                                          \
        const f32x4 _hv = *(const f32x4*)(_hb + 4 * ((_i + rot) & 7));        \
        _Pragma("unroll")                                                     \
        for (int _e = 0; _e < 4; ++_e) {                                      \
            _s0 = fmaf(_hv[_e], wr0[_i * 4 + _e], _s0);                       \
            _s1 = fmaf(_hv[_e], wr1[_i * 4 + _e], _s1);                       \
            _s2 = fmaf(_hv[_e], wr2[_i * 4 + _e], _s2);                       \
        }                                                                     \
    }                                                                         \
    _s0 += __shfl_xor(_s0, 1); _s1 += __shfl_xor(_s1, 1);                     \
    _s2 += __shfl_xor(_s2, 1);                                                \
    _s0 += __shfl_xor(_s0, 2); _s1 += __shfl_xor(_s1, 2);                     \
    _s2 += __shfl_xor(_s2, 2);                                                \
    const float _r = 1.f / (1.f + __expf(-(BUF[0] + _s0 + bhr)));             \
    const float _z = 1.f / (1.f + __expf(-(BUF[1] + _s1 + bhz)));             \
    float _a = BUF[2] + _r * (_s2 + bhn);                                     \
    _a = fminf(fmaxf(_a, -15.f), 15.f);                                       \
    const float _e2 = __expf(2.f * _a);                                       \
    const float _n = (_e2 - 1.f) / (_e2 + 1.f);                               \
    hreg = (1.f - _z) * _n + _z * hreg;                                       \
    if (lq == 0) {                                                            \
        if (isL0) hseq[((size_t)(b * 512 + _t)) * 128 + j] = hreg;            \
        sm.hsh[P_ ^ 1][j] = hreg;                                             \
    }                                                                         \
    R_ISSUE(BUF, _t + 2);                                                     \
    const bool _pub = isL0 && ((_t & 15) == 15);                              \
    if (_pub) asm volatile("s_waitcnt vmcnt(3)" ::: "memory");                \
    bar_lds();                                                                \
    if (_pub && tid == 0) {                                                   \
        __threadfence();                                                      \
        atomicExch(&setflag[b * 32 + (_t >> 4)], 1);                          \
    }                                                                         \
} while (0)

__device__ void recur_role(
    bool isL0, int b, const float* __restrict__ xg,
    const float* __restrict__ whh, const float* __restrict__ bhh,
    float* __restrict__ hseq, int* __restrict__ setflag, int* __restrict__ waitflag,
    const float* __restrict__ wfc1, const float* __restrict__ bfc1,
    const float* __restrict__ wfc2, const float* __restrict__ bfc2,
    float* __restrict__ out, SmemRecur& sm)
{
    const int tid = threadIdx.x;        // 0..511
    const int j   = tid >> 2;           // hidden unit 0..127
    const int lq  = tid & 3;            // k-quarter 0..3
    const int rot = 2 * lq;             // bank-rotation for h reads

    // per-lane weights (rotated chunk order to match h reads): 96 VGPR
    float wr0[32], wr1[32], wr2[32];
    {
        const float* pr = whh + (size_t)(j)       * 128 + 32 * lq;
        const float* pz = whh + (size_t)(128 + j) * 128 + 32 * lq;
        const float* pn = whh + (size_t)(256 + j) * 128 + 32 * lq;
#pragma unroll
        for (int i = 0; i < 8; ++i) {
            const int c4 = 4 * ((i + rot) & 7);
            f32x4 v0 = *(const f32x4*)(pr + c4);
            f32x4 v1 = *(const f32x4*)(pz + c4);
            f32x4 v2 = *(const f32x4*)(pn + c4);
#pragma unroll
            for (int e = 0; e < 4; ++e) {
                wr0[i * 4 + e] = v0[e];
                wr1[i * 4 + e] = v1[e];
                wr2[i * 4 + e] = v2[e];
            }
        }
    }
    const float bhr = bhh[j], bhz = bhh[128 + j], bhn = bhh[256 + j];
    float hreg = 0.f;
    const float* xgb = xg + (size_t)b * 512 * 384;

    if (tid < 128) sm.hsh[0][tid] = 0.f;
    float pA[3], pB[3];
    R_ISSUE(pA, 0);   // L1: waits chunk 0
    R_ISSUE(pB, 1);
    __syncthreads();

    for (int gp = 0; gp < 256; ++gp) {
        R_STEP(2 * gp,     pA, 0);
        R_STEP(2 * gp + 1, pB, 1);
    }

    if (!isL0 && tid < 64) {   // fused MLP head (h(511) is in hsh[0])
        const float* wv = wfc1 + tid * 128;
        float acc = bfc1[tid];
#pragma unroll 8
        for (int c = 0; c < 128; ++c) acc = fmaf(sm.hsh[0][c], wv[c], acc);
        float p = fmaxf(acc, 0.f) * wfc2[tid];
#pragma unroll
        for (int off = 32; off > 0; off >>= 1) p += __shfl_down(p, off);
        if (tid == 0) out[b] = p + bfc2[0];
    }
}

__device__ void worker_role(
    int wk, const float* __restrict__ h1, float* __restrict__ xg,
    const float* __restrict__ wih1, const float* __restrict__ bih1,
    int* __restrict__ h1flag, int* __restrict__ xgflag, SmemGemm& sm)
{
    const int tid = threadIdx.x, lane = tid & 63, w = tid >> 6;   // 8 waves
    const int rsel = lane & 15, koff = (lane >> 4) * 8;

    // persistent W_ih1 fragments: wave w owns n-frags {3w, 3w+1, 3w+2}
    s16x8 bh[3][4], bl[3][4];
    float bias[3];
#pragma unroll
    for (int nfi = 0; nfi < 3; ++nfi) {
        const int n = (3 * w + nfi) * 16 + rsel;
        bias[nfi] = bih1[n];
#pragma unroll
        for (int ks = 0; ks < 4; ++ks) {
            const float* p = wih1 + n * 128 + ks * 32 + koff;
            f32x4 v0 = *(const f32x4*)p, v1 = *(const f32x4*)(p + 4);
            float fv[8] = {v0[0],v0[1],v0[2],v0[3], v1[0],v1[1],v1[2],v1[3]};
            s16x8 hh, ll;
#pragma unroll
            for (int i = 0; i < 8; ++i) {
                u16 h = f2bf(fv[i]); hh[i] = (short)h; ll[i] = (short)f2bf(fv[i] - bf2f(h));
            }
            bh[nfi][ks] = hh; bl[nfi][ks] = ll;
        }
    }

    for (int jt = wk; jt < 2048; jt += 128) {
        const int c = jt >> 6, b = jt & 63;     // chunk 0..31, batch 0..63
        if (tid == 0) {
            while (atomicAdd(&h1flag[b * 32 + c], 0) == 0) __builtin_amdgcn_s_sleep(8);
            __threadfence();
        }
        __syncthreads();
        // stage A = h1 rows (b, 16c..16c+15): fp32 -> split bf16 hi/lo in LDS
        if (tid < 256) {
            const int r = tid >> 4, c0 = (tid & 15) * 8;
            const float* p = h1 + ((size_t)(b * 512 + c * 16 + r)) * 128 + c0;
            f32x4 v0 = *(const f32x4*)p, v1 = *(const f32x4*)(p + 4);
            float fv[8] = {v0[0],v0[1],v0[2],v0[3], v1[0],v1[1],v1[2],v1[3]};
            s16x8 hh, ll;
#pragma unroll
            for (int i = 0; i < 8; ++i) {
                u16 h = f2bf(fv[i]); hh[i] = (short)h; ll[i] = (short)f2bf(fv[i] - bf2f(h));
            }
            const int sc = c0 ^ ((r & 7) << 3);   // XOR-swizzle (T2)
            *(s16x8*)&sm.ah[r * 128 + sc] = hh;
            *(s16x8*)&sm.al[r * 128 + sc] = ll;
        }
        __syncthreads();

        f32x4 acc[3];
        const f32x4 vz = {0.f, 0.f, 0.f, 0.f};
        acc[0] = vz; acc[1] = vz; acc[2] = vz;
#pragma unroll
        for (int ks = 0; ks < 4; ++ks) {
            const int si = rsel * 128 + ((ks * 32 + koff) ^ ((rsel & 7) << 3));
            s16x8 a_h = *(const s16x8*)&sm.ah[si];
            s16x8 a_l = *(const s16x8*)&sm.al[si];
#pragma unroll
            for (int nfi = 0; nfi < 3; ++nfi) {
                acc[nfi] = __builtin_amdgcn_mfma_f32_16x16x32_bf16(a_h, bh[nfi][ks], acc[nfi], 0, 0, 0);
                acc[nfi] = __builtin_amdgcn_mfma_f32_16x16x32_bf16(a_h, bl[nfi][ks], acc[nfi], 0, 0, 0);
                acc[nfi] = __builtin_amdgcn_mfma_f32_16x16x32_bf16(a_l, bh[nfi][ks], acc[nfi], 0, 0, 0);
            }
        }
        // epilogue: xg1 rows overwrite consumed xg0 rows (safe: flag order)
#pragma unroll
        for (int nfi = 0; nfi < 3; ++nfi) {
            const int n = (3 * w + nfi) * 16 + rsel;
#pragma unroll
            for (int jj = 0; jj < 4; ++jj) {
                const int m = (lane >> 4) * 4 + jj;
                xg[((size_t)(b * 512 + c * 16 + m)) * 384 + n] = acc[nfi][jj] + bias[nfi];
            }
        }
        __syncthreads();   // drains stores (vmcnt0) + LDS reuse safety
        if (tid == 0) {
            __threadfence();
            atomicExch(&xgflag[b * 32 + c], 1);
        }
    }
}

__global__ __launch_bounds__(512, 2)
void k_fused(float* __restrict__ xg, float* __restrict__ h1,
             const float* __restrict__ whh0, const float* __restrict__ bhh0,
             const float* __restrict__ wih1, const float* __restrict__ bih1,
             const float* __restrict__ whh1, const float* __restrict__ bhh1,
             const float* __restrict__ wfc1, const float* __restrict__ bfc1,
             const float* __restrict__ wfc2, const float* __restrict__ bfc2,
             float* __restrict__ out, int* __restrict__ h1flag, int* __restrict__ xgflag)
{
    __shared__ __align__(16) Smem sm;
    const int bid = blockIdx.x;
    if (bid < 64) {
        recur_role(true, bid, xg, whh0, bhh0, h1, h1flag, nullptr,
                   nullptr, nullptr, nullptr, nullptr, nullptr, sm.r);
    } else if (bid < 128) {
        recur_role(false, bid - 64, xg, whh1, bhh1, nullptr, nullptr, xgflag,
                   wfc1, bfc1, wfc2, bfc2, out, sm.r);
    } else {
        worker_role(bid - 128, h1, xg, wih1, bih1, h1flag, xgflag, sm.g);
    }
}

extern "C" void kernel_launch(void* const* d_in, const int* in_sizes, int n_in,
                              void* d_out, int out_size, void* d_ws, size_t ws_size,
                              hipStream_t stream) {
    const float* x     = (const float*)d_in[0];
    const float* w_ih0 = (const float*)d_in[1];
    const float* w_hh0 = (const float*)d_in[2];
    const float* b_ih0 = (const float*)d_in[3];
    const float* b_hh0 = (const float*)d_in[4];
    const float* w_ih1 = (const float*)d_in[5];
    const float* w_hh1 = (const float*)d_in[6];
    const float* b_ih1 = (const float*)d_in[7];
    const float* b_hh1 = (const float*)d_in[8];
    const float* w_fc1 = (const float*)d_in[9];
    const float* b_fc1 = (const float*)d_in[10];
    const float* w_fc2 = (const float*)d_in[11];
    const float* b_fc2 = (const float*)d_in[12];
    float* out = (float*)d_out;
    (void)in_sizes; (void)n_in; (void)out_size; (void)ws_size;

    char* ws = (char*)d_ws;
    float* xg     = (float*)(ws + 0);          // 32768*384*4 (xg0, then xg1 in place)
    float* h1     = (float*)(ws + 50331648);   // 32768*128*4
    u16*   w0h    = (u16*)(ws + 67108864);     // 786432*2
    u16*   w0l    = (u16*)(ws + 68681728);     // 786432*2
    int*   h1flag = (int*)(ws + 70254592);     // 2048 ints
    int*   xgflag = h1flag + 2048;             // 2048 ints

    k_zero<<<16, 256, 0, stream>>>(h1flag, 4096);
    k_split<<<3072, 256, 0, stream>>>(w_ih0, w0h, w0l, 384 * 2048);
    k_gemm<<<768, 256, 0, stream>>>(x, w0h, w0l, b_ih0, xg, 2048);
    k_fused<<<256, 512, 0, stream>>>(xg, h1, w_hh0, b_hh0, w_ih1, b_ih1,
                                     w_hh1, b_hh1, w_fc1, b_fc1, w_fc2, b_fc2,
                                     out, h1flag, xgflag);
}

// Round 10
// 689.170 us; speedup vs baseline: 1.5718x; 1.3597x over previous
//
#include <hip/hip_runtime.h>
#include <cstdint>
#include <cstddef>

typedef float f32x4 __attribute__((ext_vector_type(4)));
typedef float f32x2 __attribute__((ext_vector_type(2)));
typedef short s16x8 __attribute__((ext_vector_type(8)));
typedef unsigned short u16;

static __device__ __forceinline__ u16 f2bf(float f) {
    uint32_t x = __float_as_uint(f);
    x += 0x7fffu + ((x >> 16) & 1u);   // round-to-nearest-even to bf16
    return (u16)(x >> 16);
}
static __device__ __forceinline__ float bf2f(u16 h) {
    return __uint_as_float(((uint32_t)h) << 16);
}

// Raw barrier with ONLY an LDS drain (no vmcnt) — prefetch loads / hseq
// stores stay in flight across the per-step barriers.
static __device__ __forceinline__ void bar_lds() {
    asm volatile("s_waitcnt lgkmcnt(0)" ::: "memory");
    __builtin_amdgcn_s_barrier();
    asm volatile("" ::: "memory");
}

// ---------------- zero the pipeline flags (every launch; replay-safe) ------
__global__ void k_zero(int* __restrict__ p, int n) {
    int i = blockIdx.x * 256 + threadIdx.x;
    if (i < n) p[i] = 0;
}

// ---------------- split fp32 -> bf16 hi/lo ----------------
__global__ void k_split(const float* __restrict__ src, u16* __restrict__ hi,
                        u16* __restrict__ lo, int n) {
    int i = blockIdx.x * 256 + threadIdx.x;
    if (i < n) {
        float f = src[i];
        u16 h = f2bf(f);
        hi[i] = h;
        lo[i] = f2bf(f - bf2f(h));
    }
}

// ---------------- split-bf16 GEMM (layer-0 input projection) ----------------
__global__ __launch_bounds__(256, 2)
void k_gemm(const float* __restrict__ A, const u16* __restrict__ Wh,
            const u16* __restrict__ Wl, const float* __restrict__ bias,
            float* __restrict__ C, int K) {
    __shared__ __align__(16) u16 sm[32768];   // 64 KB

    const int tid  = threadIdx.x;
    const int lane = tid & 63;
    const int wave = tid >> 6;
    const int wm = wave >> 1, wn = wave & 1;

    int g = blockIdx.x;                 // 0..767
    int xcd = g & 7, ix = g >> 3;       // 96 per xcd
    int q3 = ix / 3;
    int mb = xcd + 8 * q3;              // 0..255
    int nb = ix - 3 * q3;               // 0..2
    const long m0 = (long)mb * 128;
    const int  n0 = nb * 128;

    f32x4 acc[4][4];
    const f32x4 vzero = {0.f, 0.f, 0.f, 0.f};
#pragma unroll
    for (int i = 0; i < 4; ++i)
#pragma unroll
        for (int j = 0; j < 4; ++j) acc[i][j] = vzero;

    const int ar = tid >> 1;
    const int ac = (tid & 1) * 16;
    const float* aptr = A + (m0 + ar) * (long)K + ac;
    const int br = tid >> 2;
    const int bc = (tid & 3) * 8;
    const u16* bhp = Wh + (long)(n0 + br) * K + bc;
    const u16* blp = Wl + (long)(n0 + br) * K + bc;

    const int ksteps = K >> 5;
    f32x4 a0, a1, a2, a3;

    {
        a0 = *(const f32x4*)(aptr + 0);
        a1 = *(const f32x4*)(aptr + 4);
        a2 = *(const f32x4*)(aptr + 8);
        a3 = *(const f32x4*)(aptr + 12);
#pragma unroll
        for (int c = 0; c < 2; ++c) {
            const u16* sh = bhp + (long)(c * 64) * K;
            const u16* sl = blp + (long)(c * 64) * K;
            u16* dh = &sm[8192  + c * 2048 + wave * 512];
            u16* dl = &sm[12288 + c * 2048 + wave * 512];
            __builtin_amdgcn_global_load_lds((const __attribute__((address_space(1))) void*)sh,
                                             (__attribute__((address_space(3))) void*)dh, 16, 0, 0);
            __builtin_amdgcn_global_load_lds((const __attribute__((address_space(1))) void*)sl,
                                             (__attribute__((address_space(3))) void*)dl, 16, 0, 0);
        }
        float fr[16] = {a0.x,a0.y,a0.z,a0.w, a1.x,a1.y,a1.z,a1.w,
                        a2.x,a2.y,a2.z,a2.w, a3.x,a3.y,a3.z,a3.w};
        s16x8 h0, h1, l0, l1;
#pragma unroll
        for (int i = 0; i < 8; ++i) {
            u16 hh = f2bf(fr[i]);     h0[i] = (short)hh; l0[i] = (short)f2bf(fr[i] - bf2f(hh));
            u16 hh2 = f2bf(fr[8+i]);  h1[i] = (short)hh2; l1[i] = (short)f2bf(fr[8+i] - bf2f(hh2));
        }
        u16* dh = &sm[ar * 32 + ac];
        u16* dl = &sm[4096 + ar * 32 + ac];
        *(s16x8*)dh = h0; *(s16x8*)(dh + 8) = h1;
        *(s16x8*)dl = l0; *(s16x8*)(dl + 8) = l1;
    }
    __syncthreads();

    for (int ks = 0; ks < ksteps; ++ks) {
        const int cur = ks & 1, nxt = cur ^ 1;
        const bool more = (ks + 1 < ksteps);
        if (more) {
            const int k0 = (ks + 1) << 5;
            a0 = *(const f32x4*)(aptr + k0 + 0);
            a1 = *(const f32x4*)(aptr + k0 + 4);
            a2 = *(const f32x4*)(aptr + k0 + 8);
            a3 = *(const f32x4*)(aptr + k0 + 12);
#pragma unroll
            for (int c = 0; c < 2; ++c) {
                const u16* sh = bhp + (long)(c * 64) * K + k0;
                const u16* sl = blp + (long)(c * 64) * K + k0;
                u16* dh = &sm[nxt * 16384 + 8192  + c * 2048 + wave * 512];
                u16* dl = &sm[nxt * 16384 + 12288 + c * 2048 + wave * 512];
                __builtin_amdgcn_global_load_lds((const __attribute__((address_space(1))) void*)sh,
                                                 (__attribute__((address_space(3))) void*)dh, 16, 0, 0);
                __builtin_amdgcn_global_load_lds((const __attribute__((address_space(1))) void*)sl,
                                                 (__attribute__((address_space(3))) void*)dl, 16, 0, 0);
            }
        }
        {
            const u16* base = &sm[cur * 16384];
            const int koff = (lane >> 4) * 8;
            const int rsel = lane & 15;
            s16x8 ah[4], al[4];
#pragma unroll
            for (int f = 0; f < 4; ++f) {
                int row = wm * 64 + f * 16 + rsel;
                ah[f] = *(const s16x8*)&base[row * 32 + koff];
                al[f] = *(const s16x8*)&base[4096 + row * 32 + koff];
            }
#pragma unroll
            for (int j = 0; j < 4; ++j) {
                int row = wn * 64 + j * 16 + rsel;
                s16x8 bh = *(const s16x8*)&base[8192  + row * 32 + koff];
                s16x8 bl = *(const s16x8*)&base[12288 + row * 32 + koff];
#pragma unroll
                for (int f = 0; f < 4; ++f) {
                    acc[f][j] = __builtin_amdgcn_mfma_f32_16x16x32_bf16(ah[f], bh, acc[f][j], 0, 0, 0);
                    acc[f][j] = __builtin_amdgcn_mfma_f32_16x16x32_bf16(ah[f], bl, acc[f][j], 0, 0, 0);
                    acc[f][j] = __builtin_amdgcn_mfma_f32_16x16x32_bf16(al[f], bh, acc[f][j], 0, 0, 0);
                }
            }
        }
        if (more) {
            float fr[16] = {a0.x,a0.y,a0.z,a0.w, a1.x,a1.y,a1.z,a1.w,
                            a2.x,a2.y,a2.z,a2.w, a3.x,a3.y,a3.z,a3.w};
            s16x8 h0, h1, l0, l1;
#pragma unroll
            for (int i = 0; i < 8; ++i) {
                u16 hh = f2bf(fr[i]);     h0[i] = (short)hh; l0[i] = (short)f2bf(fr[i] - bf2f(hh));
                u16 hh2 = f2bf(fr[8+i]);  h1[i] = (short)hh2; l1[i] = (short)f2bf(fr[8+i] - bf2f(hh2));
            }
            u16* dh = &sm[nxt * 16384 + ar * 32 + ac];
            u16* dl = &sm[nxt * 16384 + 4096 + ar * 32 + ac];
            *(s16x8*)dh = h0; *(s16x8*)(dh + 8) = h1;
            *(s16x8*)dl = l0; *(s16x8*)(dl + 8) = l1;
        }
        __syncthreads();
    }

    const int r0 = (lane >> 4) << 2;
    const int cn = lane & 15;
#pragma unroll
    for (int f = 0; f < 4; ++f) {
        const long mrow = m0 + wm * 64 + f * 16 + r0;
#pragma unroll
        for (int j = 0; j < 4; ++j) {
            const int n = n0 + wn * 64 + j * 16 + cn;
            const float bv = bias[n];
            float* o = C + mrow * 384 + n;
#pragma unroll
            for (int jj = 0; jj < 4; ++jj) o[(long)jj * 384] = acc[f][j][jj] + bv;
        }
    }
}

// =================== fused pipeline kernel (r5 structure + readlane dot) ====
// grid = 256 blocks x 512 threads, 1 block/CU (LDS-forced).
//   blocks   0..63 : layer-0 recurrence (produce h1 + flag per 16-step chunk)
//   blocks  64..127: layer-1 recurrence (consume xgflag) + MLP head
//   blocks 128..255: GEMM workers: xg1 = h1 @ w_ih1^T + b_ih1 (W_ih1 in regs)
//
// Recurrence (8 waves): wave w owns k-slice [16w,16w+16); lane owns gates
// 6*lane..6*lane+5. h fetch = ONE ds_read_b64 per lane (hsh[2*lane..]) +
// 16 v_readlane with SGPR lane index (readfirstlane(8w+k), hoisted out of
// the t-loop) -> dot-phase LDS reads drop 32 b128 -> 8 b64 per step.

struct SmemRecur { float hsh[128]; float hp[8][384]; };
struct SmemGemm  { u16 ah[16 * 128]; u16 al[16 * 128]; };
union Smem {
    SmemRecur r;
    SmemGemm  g;
    char force_one_block_per_cu[98304];   // 96KB: strictly 1 block/CU
};

#define R_ISSUE(BUF, G) do {                                                  \
    const int _G = (G);                                                       \
    if (_G < 128 && tid < 128) {                                              \
        if (!isL0 && (_G & 3) == 0) {                                         \
            if ((tid & 63) == 0) {                                            \
                while (atomicAdd(&waitflag[b * 32 + (_G >> 2)], 0) == 0)      \
                    __builtin_amdgcn_s_sleep(8);                              \
            }                                                                 \
            __threadfence();                                                  \
        }                                                                     \
        const float* _p = xgb + (size_t)(4 * _G) * 384 + tid;                 \
        BUF[0] = _p[0];    BUF[1] = _p[128];   BUF[2]  = _p[256];             \
        BUF[3] = _p[384];  BUF[4] = _p[512];   BUF[5]  = _p[640];             \
        BUF[6] = _p[768];  BUF[7] = _p[896];   BUF[8]  = _p[1024];            \
        BUF[9] = _p[1152]; BUF[10] = _p[1280]; BUF[11] = _p[1408];            \
    } } while (0)

#define R_STEP(T, BUF, J) do {                                                \
    const int _t = (T);                                                       \
    const f32x2 _h2 = *(const f32x2*)(sm.hsh + 2 * lane);                     \
    float _ha[16];                                                            \
    _Pragma("unroll")                                                         \
    for (int _i = 0; _i < 8; ++_i) {                                          \
        _ha[2 * _i] = __uint_as_float(                                        \
            __builtin_amdgcn_readlane(__float_as_uint(_h2[0]), rlx[_i]));     \
        _ha[2 * _i + 1] = __uint_as_float(                                    \
            __builtin_amdgcn_readlane(__float_as_uint(_h2[1]), rlx[_i]));     \
    }                                                                         \
    float _s0=0.f,_s1=0.f,_s2=0.f,_s3=0.f,_s4=0.f,_s5=0.f;                    \
    _Pragma("unroll")                                                         \
    for (int _i = 0; _i < 16; ++_i) {                                         \
        const float _hv = _ha[_i];                                            \
        _s0 = fmaf(_hv, wr[0][_i], _s0); _s1 = fmaf(_hv, wr[1][_i], _s1);     \
        _s2 = fmaf(_hv, wr[2][_i], _s2); _s3 = fmaf(_hv, wr[3][_i], _s3);     \
        _s4 = fmaf(_hv, wr[4][_i], _s4); _s5 = fmaf(_hv, wr[5][_i], _s5);     \
    }                                                                         \
    *(f32x2*)&sm.hp[w][g6 + 0] = (f32x2){_s0, _s1};                           \
    *(f32x2*)&sm.hp[w][g6 + 2] = (f32x2){_s2, _s3};                           \
    *(f32x2*)&sm.hp[w][g6 + 4] = (f32x2){_s4, _s5};                           \
    const bool _pub = isL0 && _t > 0 && (_t & 15) == 0;                       \
    if (_pub && tid < 128) asm volatile("s_waitcnt vmcnt(12)" ::: "memory");  \
    bar_lds();                                                                \
    if (_pub && tid == 0) {                                                   \
        __threadfence();                                                      \
        atomicExch(&setflag[b * 32 + ((_t >> 4) - 1)], 1);                    \
    }                                                                         \
    if (tid < 128) {                                                          \
        const int _c = tid;                                                   \
        float _hr = bhr, _hz = bhz, _hn = bhn;                                \
        _Pragma("unroll")                                                     \
        for (int _q = 0; _q < 8; ++_q) {                                      \
            _hr += sm.hp[_q][_c];                                             \
            _hz += sm.hp[_q][128 + _c];                                       \
            _hn += sm.hp[_q][256 + _c];                                       \
        }                                                                     \
        const float _xr = BUF[(J) * 3 + 0];                                   \
        const float _xz = BUF[(J) * 3 + 1];                                   \
        const float _xn = BUF[(J) * 3 + 2];                                   \
        const float _r = 1.f / (1.f + __expf(-(_xr + _hr)));                  \
        const float _z = 1.f / (1.f + __expf(-(_xz + _hz)));                  \
        float _a = _xn + _r * _hn;                                            \
        _a = fminf(fmaxf(_a, -15.f), 15.f);                                   \
        const float _e = __expf(2.f * _a);                                    \
        const float _n = (_e - 1.f) / (_e + 1.f);                             \
        hreg = (1.f - _z) * _n + _z * hreg;                                   \
        sm.hsh[_c] = hreg;                                                    \
        if (isL0) hseq[((size_t)(b * 512 + _t)) * 128 + _c] = hreg;           \
    }                                                                         \
    bar_lds();                                                                \
} while (0)

__device__ void recur_role(
    bool isL0, int b, const float* __restrict__ xg,
    const float* __restrict__ whh, const float* __restrict__ bhh,
    float* __restrict__ hseq, int* __restrict__ setflag, int* __restrict__ waitflag,
    const float* __restrict__ wfc1, const float* __restrict__ bfc1,
    const float* __restrict__ wfc2, const float* __restrict__ bfc2,
    float* __restrict__ out, SmemRecur& sm)
{
    const int tid  = threadIdx.x;       // 0..511
    const int w    = tid >> 6;          // k-slice 0..7 (wave-uniform)
    const int lane = tid & 63;
    const int g6   = 6 * lane;          // first of this lane's 6 gates

    // SGPR lane indices for the readlane h-extract (hoisted, step-invariant)
    int rlx[8];
#pragma unroll
    for (int k = 0; k < 8; ++k)
        rlx[k] = __builtin_amdgcn_readfirstlane(8 * w + k);

    // per-lane weights: wr[j][i] = whh[(g6+j)*128 + 16w + i]
    float wr[6][16];
#pragma unroll
    for (int j = 0; j < 6; ++j) {
        const float* p = whh + (size_t)(g6 + j) * 128 + 16 * w;
#pragma unroll
        for (int i4 = 0; i4 < 4; ++i4) {
            f32x4 v = *(const f32x4*)(p + 4 * i4);
            wr[j][4*i4+0] = v[0]; wr[j][4*i4+1] = v[1];
            wr[j][4*i4+2] = v[2]; wr[j][4*i4+3] = v[3];
        }
    }
    float bhr = 0.f, bhz = 0.f, bhn = 0.f, hreg = 0.f;
    if (tid < 128) {
        bhr = bhh[tid]; bhz = bhh[128 + tid]; bhn = bhh[256 + tid];
        sm.hsh[tid] = 0.f;
    }
    const float* xgb = xg + (size_t)b * 512 * 384;

    float pA[12], pB[12];
    R_ISSUE(pA, 0);
    R_ISSUE(pB, 1);
    __syncthreads();   // hsh init visible

    for (int gp = 0; gp < 64; ++gp) {
        const int t0 = gp * 8;
        R_STEP(t0 + 0, pA, 0); R_STEP(t0 + 1, pA, 1);
        R_STEP(t0 + 2, pA, 2); R_STEP(t0 + 3, pA, 3);
        R_ISSUE(pA, 2 * gp + 2);
        R_STEP(t0 + 4, pB, 0); R_STEP(t0 + 5, pB, 1);
        R_STEP(t0 + 6, pB, 2); R_STEP(t0 + 7, pB, 3);
        R_ISSUE(pB, 2 * gp + 3);
    }

    if (isL0) {   // final chunk publish
        if (tid < 128) asm volatile("s_waitcnt vmcnt(0)" ::: "memory");
        __syncthreads();
        if (tid == 0) { __threadfence(); atomicExch(&setflag[b * 32 + 31], 1); }
    }

    if (!isL0 && tid < 64) {   // fused MLP head
        const float* wv = wfc1 + tid * 128;
        float acc = bfc1[tid];
#pragma unroll 8
        for (int c = 0; c < 128; ++c) acc = fmaf(sm.hsh[c], wv[c], acc);
        float p = fmaxf(acc, 0.f) * wfc2[tid];
#pragma unroll
        for (int off = 32; off > 0; off >>= 1) p += __shfl_down(p, off);
        if (tid == 0) out[b] = p + bfc2[0];
    }
}

__device__ void worker_role(
    int wk, const float* __restrict__ h1, float* __restrict__ xg,
    const float* __restrict__ wih1, const float* __restrict__ bih1,
    int* __restrict__ h1flag, int* __restrict__ xgflag, SmemGemm& sm)
{
    const int tid = threadIdx.x, lane = tid & 63, w = tid >> 6;   // 8 waves
    const int rsel = lane & 15, koff = (lane >> 4) * 8;

    // persistent W_ih1 fragments: wave w owns n-frags {3w, 3w+1, 3w+2}
    s16x8 bh[3][4], bl[3][4];
    float bias[3];
#pragma unroll
    for (int nfi = 0; nfi < 3; ++nfi) {
        const int n = (3 * w + nfi) * 16 + rsel;
        bias[nfi] = bih1[n];
#pragma unroll
        for (int ks = 0; ks < 4; ++ks) {
            const float* p = wih1 + n * 128 + ks * 32 + koff;
            f32x4 v0 = *(const f32x4*)p, v1 = *(const f32x4*)(p + 4);
            float fv[8] = {v0[0],v0[1],v0[2],v0[3], v1[0],v1[1],v1[2],v1[3]};
            s16x8 hh, ll;
#pragma unroll
            for (int i = 0; i < 8; ++i) {
                u16 h = f2bf(fv[i]); hh[i] = (short)h; ll[i] = (short)f2bf(fv[i] - bf2f(h));
            }
            bh[nfi][ks] = hh; bl[nfi][ks] = ll;
        }
    }

    for (int jt = wk; jt < 2048; jt += 128) {
        const int c = jt >> 6, b = jt & 63;     // chunk 0..31, batch 0..63
        if (tid == 0) {
            while (atomicAdd(&h1flag[b * 32 + c], 0) == 0) __builtin_amdgcn_s_sleep(8);
            __threadfence();
        }
        __syncthreads();
        // stage A = h1 rows (b, 16c..16c+15): fp32 -> split bf16 hi/lo in LDS
        if (tid < 256) {
            const int r = tid >> 4, c0 = (tid & 15) * 8;
            const float* p = h1 + ((size_t)(b * 512 + c * 16 + r)) * 128 + c0;
            f32x4 v0 = *(const f32x4*)p, v1 = *(const f32x4*)(p + 4);
            float fv[8] = {v0[0],v0[1],v0[2],v0[3], v1[0],v1[1],v1[2],v1[3]};
            s16x8 hh, ll;
#pragma unroll
            for (int i = 0; i < 8; ++i) {
                u16 h = f2bf(fv[i]); hh[i] = (short)h; ll[i] = (short)f2bf(fv[i] - bf2f(h));
            }
            const int sc = c0 ^ ((r & 7) << 3);   // XOR-swizzle (T2)
            *(s16x8*)&sm.ah[r * 128 + sc] = hh;
            *(s16x8*)&sm.al[r * 128 + sc] = ll;
        }
        __syncthreads();

        f32x4 acc[3];
        const f32x4 vz = {0.f, 0.f, 0.f, 0.f};
        acc[0] = vz; acc[1] = vz; acc[2] = vz;
#pragma unroll
        for (int ks = 0; ks < 4; ++ks) {
            const int si = rsel * 128 + ((ks * 32 + koff) ^ ((rsel & 7) << 3));
            s16x8 a_h = *(const s16x8*)&sm.ah[si];
            s16x8 a_l = *(const s16x8*)&sm.al[si];
#pragma unroll
            for (int nfi = 0; nfi < 3; ++nfi) {
                acc[nfi] = __builtin_amdgcn_mfma_f32_16x16x32_bf16(a_h, bh[nfi][ks], acc[nfi], 0, 0, 0);
                acc[nfi] = __builtin_amdgcn_mfma_f32_16x16x32_bf16(a_h, bl[nfi][ks], acc[nfi], 0, 0, 0);
                acc[nfi] = __builtin_amdgcn_mfma_f32_16x16x32_bf16(a_l, bh[nfi][ks], acc[nfi], 0, 0, 0);
            }
        }
        // epilogue: xg1 rows overwrite consumed xg0 rows (safe: flag order)
#pragma unroll
        for (int nfi = 0; nfi < 3; ++nfi) {
            const int n = (3 * w + nfi) * 16 + rsel;
#pragma unroll
            for (int jj = 0; jj < 4; ++jj) {
                const int m = (lane >> 4) * 4 + jj;
                xg[((size_t)(b * 512 + c * 16 + m)) * 384 + n] = acc[nfi][jj] + bias[nfi];
            }
        }
        __syncthreads();   // drains stores (vmcnt0) + LDS reuse safety
        if (tid == 0) {
            __threadfence();
            atomicExch(&xgflag[b * 32 + c], 1);
        }
    }
}

__global__ __launch_bounds__(512, 2)
void k_fused(float* __restrict__ xg, float* __restrict__ h1,
             const float* __restrict__ whh0, const float* __restrict__ bhh0,
             const float* __restrict__ wih1, const float* __restrict__ bih1,
             const float* __restrict__ whh1, const float* __restrict__ bhh1,
             const float* __restrict__ wfc1, const float* __restrict__ bfc1,
             const float* __restrict__ wfc2, const float* __restrict__ bfc2,
             float* __restrict__ out, int* __restrict__ h1flag, int* __restrict__ xgflag)
{
    __shared__ __align__(16) Smem sm;
    const int bid = blockIdx.x;
    if (bid < 64) {
        recur_role(true, bid, xg, whh0, bhh0, h1, h1flag, nullptr,
                   nullptr, nullptr, nullptr, nullptr, nullptr, sm.r);
    } else if (bid < 128) {
        recur_role(false, bid - 64, xg, whh1, bhh1, nullptr, nullptr, xgflag,
                   wfc1, bfc1, wfc2, bfc2, out, sm.r);
    } else {
        worker_role(bid - 128, h1, xg, wih1, bih1, h1flag, xgflag, sm.g);
    }
}

extern "C" void kernel_launch(void* const* d_in, const int* in_sizes, int n_in,
                              void* d_out, int out_size, void* d_ws, size_t ws_size,
                              hipStream_t stream) {
    const float* x     = (const float*)d_in[0];
    const float* w_ih0 = (const float*)d_in[1];
    const float* w_hh0 = (const float*)d_in[2];
    const float* b_ih0 = (const float*)d_in[3];
    const float* b_hh0 = (const float*)d_in[4];
    const float* w_ih1 = (const float*)d_in[5];
    const float* w_hh1 = (const float*)d_in[6];
    const float* b_ih1 = (const float*)d_in[7];
    const float* b_hh1 = (const float*)d_in[8];
    const float* w_fc1 = (const float*)d_in[9];
    const float* b_fc1 = (const float*)d_in[10];
    const float* w_fc2 = (const float*)d_in[11];
    const float* b_fc2 = (const float*)d_in[12];
    float* out = (float*)d_out;
    (void)in_sizes; (void)n_in; (void)out_size; (void)ws_size;

    char* ws = (char*)d_ws;
    float* xg     = (float*)(ws + 0);          // 32768*384*4 (xg0, then xg1 in place)
    float* h1     = (float*)(ws + 50331648);   // 32768*128*4
    u16*   w0h    = (u16*)(ws + 67108864);     // 786432*2
    u16*   w0l    = (u16*)(ws + 68681728);     // 786432*2
    int*   h1flag = (int*)(ws + 70254592);     // 2048 ints
    int*   xgflag = h1flag + 2048;             // 2048 ints

    k_zero<<<16, 256, 0, stream>>>(h1flag, 4096);
    k_split<<<3072, 256, 0, stream>>>(w_ih0, w0h, w0l, 384 * 2048);
    k_gemm<<<768, 256, 0, stream>>>(x, w0h, w0l, b_ih0, xg, 2048);
    k_fused<<<256, 512, 0, stream>>>(xg, h1, w_hh0, b_hh0, w_ih1, b_ih1,
                                     w_hh1, b_hh1, w_fc1, b_fc1, w_fc2, b_fc2,
                                     out, h1flag, xgflag);
}